// Round 11
// baseline (323.196 us; speedup 1.0000x reference)
//
#include <hip/hip_runtime.h>

#define D_MODEL 1024
#define D_FFN   4096
#define NH      16
#define DH      64
#define BB      2
#define LL      2048
#define MROWS   (BB * LL)   // 4096

typedef unsigned short u16;
typedef unsigned int   u32;
typedef short bf16x8 __attribute__((ext_vector_type(8)));
typedef float f32x4  __attribute__((ext_vector_type(4)));

__device__ __forceinline__ float bf2f(u16 u) {
    union { u32 i; float f; } v;
    v.i = ((u32)u) << 16;
    return v.f;
}
__device__ __forceinline__ u16 f2bf(float f) {
    union { float f; u32 i; } v;
    v.f = f;
    u32 x = v.i;
    x += 0x7fffu + ((x >> 16) & 1u);   // round to nearest even
    return (u16)(x >> 16);
}
// pack high-16s of two floats (truncating bf16): {lo=a, hi=b}
__device__ __forceinline__ u32 pack_bf_trunc(float a, float b) {
    return __builtin_amdgcn_perm(__float_as_uint(b), __float_as_uint(a),
                                 0x07060302u);
}

// async global->LDS, 16B per lane; ldsptr must be wave-uniform (HW adds lane*16)
typedef const __attribute__((address_space(1))) u32 gu32;
typedef __attribute__((address_space(3))) u32 lu32;
__device__ __forceinline__ void gload_lds16(const void* g, void* l) {
    __builtin_amdgcn_global_load_lds((gu32*)g, (lu32*)l, 16, 0, 0);
}

// ---------------------------------------------------------------------------
// 64x64 fp32->bf16 transpose tile helper (LDS tile passed in)
// ---------------------------------------------------------------------------
__device__ __forceinline__ void wt_tile(
    const float* __restrict__ W, u16* __restrict__ Wt,
    int K, int N, int t, int tid, float* tile /* 64*65 floats */)
{
    const int ntiles = N >> 6;
    const int n0 = (t % ntiles) * 64;
    const int k0 = (t / ntiles) * 64;

    int kr = tid >> 4;             // 0..15
    int nc = (tid & 15) * 4;       // 0..60
    #pragma unroll
    for (int p = 0; p < 4; ++p) {
        float4 v = *(const float4*)&W[(size_t)(k0 + kr + p * 16) * N + n0 + nc];
        tile[(kr + p * 16) * 65 + nc + 0] = v.x;
        tile[(kr + p * 16) * 65 + nc + 1] = v.y;
        tile[(kr + p * 16) * 65 + nc + 2] = v.z;
        tile[(kr + p * 16) * 65 + nc + 3] = v.w;
    }
    __syncthreads();

    int nr = tid >> 2;             // 0..63
    int kc = (tid & 3) * 16;       // 0..48
    u16 o[16];
    #pragma unroll
    for (int j = 0; j < 16; ++j) o[j] = f2bf(tile[(kc + j) * 65 + nr]);
    u16* dst = &Wt[(size_t)(n0 + nr) * K + k0 + kc];
    *(uint4*)dst       = *(const uint4*)&o[0];
    *(uint4*)(dst + 8) = *(const uint4*)&o[8];
}

// ---------------------------------------------------------------------------
// Prep: blocks [0,2048) convert x fp32->bf16; [2048,2816) transpose Wqkv.
// ---------------------------------------------------------------------------
__global__ __launch_bounds__(256) void prep_kernel(
    const float* __restrict__ x,    u16* __restrict__ xb,
    const float* __restrict__ Wqkv, u16* __restrict__ Wqkvt)
{
    __shared__ float tile[64 * 65];
    const int tid = threadIdx.x;
    const int bi  = blockIdx.x;

    if (bi < 2048) {   // x convert
        int i = bi * 2048 + tid * 8;
        float4 a = *(const float4*)(x + i);
        float4 b = *(const float4*)(x + i + 4);
        u16 o[8] = {f2bf(a.x), f2bf(a.y), f2bf(a.z), f2bf(a.w),
                    f2bf(b.x), f2bf(b.y), f2bf(b.z), f2bf(b.w)};
        *(uint4*)(xb + i) = *(const uint4*)o;
        return;
    }
    wt_tile(Wqkv, Wqkvt, 1024, 3072, bi - 2048, tid, tile);
}

// ---------------------------------------------------------------------------
// MFMA bf16 GEMM, m97-style, XCD remap, optional split-K. Kept for QKV
// (scatter + V-transpose epilogue) and Wo (small, split-K=2).
// ---------------------------------------------------------------------------
template <int EPI, int RF32, int OF32, int KS>
__global__ __launch_bounds__(256, 4) void gemm_bt_kernel(
    const u16* __restrict__ A, const u16* __restrict__ Bt,
    const float* __restrict__ bias, const void* __restrict__ resv,
    void* __restrict__ out0v, u16* __restrict__ out1, u16* __restrict__ out2,
    int M, int N, int K)
{
    __shared__ u16 smem[16384];    // 32 KB: sA|sB staging; V-transpose tile
    u16* sA = smem;                // 128*64
    u16* sB = smem + 8192;         // 128*64

    const int tid  = threadIdx.x;
    const int lane = tid & 63;
    const int wave = tid >> 6;
    const int wm   = (wave & 1) * 64;
    const int wn   = (wave >> 1) * 64;
    const int quad = lane >> 4;
    const int l16  = lane & 15;

    // XCD-locality remap (requires gridDim.x % 2 == 0, gridDim.y % 4 == 0)
    const int nb  = gridDim.x;
    const int mb  = gridDim.y;
    const int f   = blockIdx.y * nb + blockIdx.x;   // dispatch-linear id
    const int xcd = f & 7;
    const int idx = f >> 3;
    const int rn  = nb >> 1;                        // region width  (tiles)
    const int rm  = mb >> 2;                        // region height (tiles)
    const int n0  = ((xcd & 1) * rn + (idx % rn)) * 128;
    const int ym  = (xcd >> 1) * rm + (idx / rn);   // 0..mb-1

    int s, m0;
    if (KS > 1) {
        const int mt = mb / KS;
        s  = ym / mt;
        m0 = (ym % mt) * 128;
    } else {
        s  = 0;
        m0 = ym * 128;
    }
    const int Kseg = K / KS;
    const int kbeg = s * Kseg;

    f32x4 acc[4][4];
    #pragma unroll
    for (int i = 0; i < 4; ++i)
        #pragma unroll
        for (int j = 0; j < 4; ++j)
            acc[i][j] = (f32x4){0.f, 0.f, 0.f, 0.f};

    const u16* Ablk = A  + (size_t)m0 * K;
    const u16* Bblk = Bt + (size_t)n0 * K;

    for (int k0 = kbeg; k0 < kbeg + Kseg; k0 += 64) {
        #pragma unroll
        for (int i = 0; i < 4; ++i) {
            int chunk = (i * 4 + wave) * 64 + lane;        // 0..1023
            int r = chunk >> 3;                            // row 0..127
            int c = (chunk & 7) ^ (r & 7);                 // swizzled k-chunk
            size_t goff = (size_t)r * K + k0 + c * 8;
            gload_lds16(Ablk + goff, &sA[(i * 4 + wave) * 512]);
            gload_lds16(Bblk + goff, &sB[(i * 4 + wave) * 512]);
        }
        __syncthreads();

        #pragma unroll
        for (int ks = 0; ks < 2; ++ks) {
            bf16x8 af[4], bfr[4];
            #pragma unroll
            for (int i = 0; i < 4; ++i) {
                int R = wm + i * 16 + l16;
                int slot = R * 8 + ((ks * 4 + quad) ^ (R & 7));
                af[i] = *(const bf16x8*)&sA[slot * 8];
            }
            #pragma unroll
            for (int j = 0; j < 4; ++j) {
                int R = wn + j * 16 + l16;
                int slot = R * 8 + ((ks * 4 + quad) ^ (R & 7));
                bfr[j] = *(const bf16x8*)&sB[slot * 8];
            }
            #pragma unroll
            for (int i = 0; i < 4; ++i)
                #pragma unroll
                for (int j = 0; j < 4; ++j)
                    acc[i][j] = __builtin_amdgcn_mfma_f32_16x16x32_bf16(
                        af[i], bfr[j], acc[i][j], 0, 0, 0);
        }
        __syncthreads();
    }

    // --- V-transpose epilogue (EPI 0, V columns): write Vt[bh][d][l] ---
    if (EPI == 0 && n0 >= 2 * D_MODEL) {
        u16* tile = smem;                       // 128x128 u16 = 32 KB
        #pragma unroll
        for (int i = 0; i < 4; ++i) {
            int rl = wm + i * 16 + quad * 4;    // local row (l) base
            #pragma unroll
            for (int j = 0; j < 4; ++j) {
                int cl = wn + j * 16 + l16;     // local col (d)
                float bv = bias[n0 + cl];
                int sx = 8 * (cl & 15);         // XOR swizzle (8-aligned)
                #pragma unroll
                for (int r = 0; r < 4; ++r)
                    tile[cl * 128 + ((rl + r) ^ sx)] = f2bf(acc[i][j][r] + bv);
            }
        }
        __syncthreads();
        int cl  = tid >> 1;                     // local col 0..127
        int rb  = (tid & 1) * 64;               // row half
        int col = n0 + cl;
        int h   = (col >> 6) & 15;
        int d   = col & 63;
        int b   = m0 >> 11;
        int l0  = (m0 & 2047) + rb;
        int sx  = 8 * (cl & 15);
        u16* dst = out2 + ((size_t)(b * NH + h) * DH + d) * LL + l0;
        #pragma unroll
        for (int u = 0; u < 8; ++u) {
            uint4 q = *(const uint4*)&tile[cl * 128 + ((rb + 8 * u) ^ sx)];
            *(uint4*)(dst + 8 * u) = q;
        }
        return;
    }

    #pragma unroll
    for (int i = 0; i < 4; ++i) {
        int rowb = m0 + wm + i * 16 + quad * 4;
        #pragma unroll
        for (int j = 0; j < 4; ++j) {
            int col = n0 + wn + j * 16 + l16;
            float bv = (EPI == 3) ? 0.f : bias[col];
            #pragma unroll
            for (int r = 0; r < 4; ++r) {
                int rr = rowb + r;
                float v = acc[i][j][r] + bv;
                if (EPI == 0) {
                    int h     = (col >> 6) & 15;
                    int d     = col & 63;
                    int b     = rr >> 11;
                    int l     = rr & 2047;
                    size_t idx2 = ((size_t)(b * NH + h) * LL + l) * DH + d;
                    u16* o0 = (u16*)out0v;
                    // Q pre-scaled by 0.125 * log2(e) so attention can use
                    // exp2 directly (softmax is scale-consistent).
                    if (col < D_MODEL)  o0[idx2]   = f2bf(v * 0.18033688f);
                    else                out1[idx2] = f2bf(v);
                } else if (EPI == 3) {
                    ((u16*)out0v)[((size_t)s * M + rr) * N + col] = f2bf(v);
                } else {
                    size_t idx2 = (size_t)rr * N + col;
                    if (EPI == 1) {
                        v += RF32 ? ((const float*)resv)[idx2]
                                  : bf2f(((const u16*)resv)[idx2]);
                    } else {  // EPI == 2: ReLU
                        v = v > 0.f ? v : 0.f;
                    }
                    if (OF32) ((float*)out0v)[idx2] = v;
                    else      ((u16*)out0v)[idx2]   = f2bf(v);
                }
            }
        }
    }
}

// ---------------------------------------------------------------------------
// R11: 256x256-tile GEMM with 4-PHASE-PER-K-TILE interleave (T3+T5; R6's
// 1-phase counted-vmcnt variant measured neutral — matches m196's documented
// null for coarse phase-split without the fine interleave).
// 512 threads = 8 waves (2M x 4N), BK=64, 128 KB LDS double-buffer.
// Per K-tile kt (buf b=kt&1), staging kt+1 -> buf b^1, 2 gloads/phase:
//   P0: ds_read af(i0..3,ks0)+bfr(ks0) | stage A q0,q1 | bar | lgkm0 |
//       setprio1 16xMFMA setprio0 | bar
//   P1: ds_read af(i4..7,ks0) (bfr reused) | stage A q2,q3 | ... 16xMFMA
//   P2: ds_read af(i0..3,ks1)+bfr(ks1)     | stage B q0,q1 | ... 16xMFMA
//   P3: ds_read af(i4..7,ks1)              | stage B q2,q3 | ... 16xMFMA |
//       vmcnt(0) | bar   <- single drain per tile, AFTER P3's MFMA so the
//       last-issued halves get ~200cyc cover; loads stay in flight across
//       the 6 intra-tile phase barriers (T4-lite).
// Race-freedom: buf-b reads guaranteed by prev tile's vmcnt(0)+barrier;
// staging targets the non-read buffer whose last reads completed before the
// preceding trailing barrier (each wave passes lgkmcnt(0) pre-MFMA);
// sched_barrier(0) after each lgkmcnt(0) pins MFMA below the wait (rule #18).
// EPI 2: relu+bias bf16. EPI 3: bf16 partial to out[s*M*N+...].
// Grids: FFN1 (16,16)=256 blocks = 1/CU; W2 split-K=4 (4,64)=256 blocks.
// ---------------------------------------------------------------------------
template <int EPI, int KS>
__global__ __launch_bounds__(512, 2) void gemm256_kernel(
    const u16* __restrict__ A, const u16* __restrict__ Bt,
    const float* __restrict__ bias, void* __restrict__ outv,
    int M, int N, int K)
{
    __shared__ u16 dsm[65536];     // 128 KB: [2 dbuf][A 16384 | B 16384] u16

    const int tid  = threadIdx.x;
    const int lane = tid & 63;
    const int wave = tid >> 6;
    const int wm   = wave >> 2;            // 0..1  (M half)
    const int wn   = wave & 3;             // 0..3  (N quarter)
    const int quad = lane >> 4;
    const int l16  = lane & 15;
    const int sw0  = quad ^ (l16 & 7);         // ks=0 chunk swizzle
    const int sw1  = (4 + quad) ^ (l16 & 7);   // ks=1

    // XCD-locality remap (nb % 2 == 0, mb % 4 == 0)
    const int nb  = gridDim.x;
    const int mb  = gridDim.y;
    const int f   = blockIdx.y * nb + blockIdx.x;
    const int xcd = f & 7;
    const int idx = f >> 3;
    const int rn  = nb >> 1;
    const int rm  = mb >> 2;
    const int n0  = ((xcd & 1) * rn + (idx % rn)) * 256;
    const int ym  = (xcd >> 1) * rm + (idx / rn);

    int s, m0;
    if (KS > 1) {
        const int mt = mb / KS;
        s  = ym / mt;
        m0 = (ym % mt) * 256;
    } else {
        s  = 0;
        m0 = ym * 256;
    }
    const int Kseg = K / KS;
    const int kbeg = s * Kseg;
    const int NT   = Kseg >> 6;            // K-tiles (16 for both call sites)

    // staging geometry: per matrix per K-tile, thread stages chunks
    // {q*512 + tid}, q=0..3 (rows q*64..q*64+63). LDS dest linear; global
    // col pre-swizzled: r = q*64 + (tid>>3), c = (tid&7) ^ (r&7).
    const int rr = tid >> 3;               // 0..63 (row within 64-row group)
    const int cc = ((tid & 7) ^ (rr & 7)) * 8;
    const u16* Asrc[4];
    const u16* Bsrc[4];
    #pragma unroll
    for (int q = 0; q < 4; ++q) {
        Asrc[q] = A  + (size_t)(m0 + q * 64 + rr) * K + kbeg + cc;
        Bsrc[q] = Bt + (size_t)(n0 + q * 64 + rr) * K + kbeg + cc;
    }

    f32x4 acc[8][4];
    #pragma unroll
    for (int i = 0; i < 8; ++i)
        #pragma unroll
        for (int j = 0; j < 4; ++j)
            acc[i][j] = (f32x4){0.f, 0.f, 0.f, 0.f};

    // prologue: stage K-tile 0 into buf 0, drain, sync
    #pragma unroll
    for (int q = 0; q < 4; ++q) {
        gload_lds16(Asrc[q], &dsm[q * 4096 + wave * 512]);
        gload_lds16(Bsrc[q], &dsm[16384 + q * 4096 + wave * 512]);
    }
    asm volatile("s_waitcnt vmcnt(0)" ::: "memory");
    asm volatile("s_barrier" ::: "memory");

    #pragma unroll 1
    for (int kt = 0; kt < NT; ++kt) {
        const u16* sAc = &dsm[(kt & 1) * 32768];
        const u16* sBc = sAc + 16384;
        u16* nbuf = &dsm[((kt + 1) & 1) * 32768];
        const bool pf = (kt + 1 < NT);
        const int koff = (kt + 1) * 64;

        bf16x8 af[4], bfr[4];

        // ---------- P0: i0..3, ks=0 ----------
        #pragma unroll
        for (int i = 0; i < 4; ++i) {
            int R = wm * 128 + i * 16 + l16;
            af[i] = *(const bf16x8*)&sAc[(R * 8 + sw0) * 8];
        }
        #pragma unroll
        for (int j = 0; j < 4; ++j) {
            int R = wn * 64 + j * 16 + l16;
            bfr[j] = *(const bf16x8*)&sBc[(R * 8 + sw0) * 8];
        }
        if (pf) {
            gload_lds16(Asrc[0] + koff, nbuf + wave * 512);
            gload_lds16(Asrc[1] + koff, nbuf + 4096 + wave * 512);
        }
        asm volatile("s_barrier" ::: "memory");
        asm volatile("s_waitcnt lgkmcnt(0)" ::: "memory");
        __builtin_amdgcn_sched_barrier(0);
        __builtin_amdgcn_s_setprio(1);
        #pragma unroll
        for (int i = 0; i < 4; ++i)
            #pragma unroll
            for (int j = 0; j < 4; ++j)
                acc[i][j] = __builtin_amdgcn_mfma_f32_16x16x32_bf16(
                    af[i], bfr[j], acc[i][j], 0, 0, 0);
        __builtin_amdgcn_s_setprio(0);
        __builtin_amdgcn_sched_barrier(0);
        asm volatile("s_barrier" ::: "memory");

        // ---------- P1: i4..7, ks=0 (bfr reused) ----------
        #pragma unroll
        for (int i = 0; i < 4; ++i) {
            int R = wm * 128 + (4 + i) * 16 + l16;
            af[i] = *(const bf16x8*)&sAc[(R * 8 + sw0) * 8];
        }
        if (pf) {
            gload_lds16(Asrc[2] + koff, nbuf + 2 * 4096 + wave * 512);
            gload_lds16(Asrc[3] + koff, nbuf + 3 * 4096 + wave * 512);
        }
        asm volatile("s_barrier" ::: "memory");
        asm volatile("s_waitcnt lgkmcnt(0)" ::: "memory");
        __builtin_amdgcn_sched_barrier(0);
        __builtin_amdgcn_s_setprio(1);
        #pragma unroll
        for (int i = 0; i < 4; ++i)
            #pragma unroll
            for (int j = 0; j < 4; ++j)
                acc[4 + i][j] = __builtin_amdgcn_mfma_f32_16x16x32_bf16(
                    af[i], bfr[j], acc[4 + i][j], 0, 0, 0);
        __builtin_amdgcn_s_setprio(0);
        __builtin_amdgcn_sched_barrier(0);
        asm volatile("s_barrier" ::: "memory");

        // ---------- P2: i0..3, ks=1 ----------
        #pragma unroll
        for (int i = 0; i < 4; ++i) {
            int R = wm * 128 + i * 16 + l16;
            af[i] = *(const bf16x8*)&sAc[(R * 8 + sw1) * 8];
        }
        #pragma unroll
        for (int j = 0; j < 4; ++j) {
            int R = wn * 64 + j * 16 + l16;
            bfr[j] = *(const bf16x8*)&sBc[(R * 8 + sw1) * 8];
        }
        if (pf) {
            gload_lds16(Bsrc[0] + koff, nbuf + 16384 + wave * 512);
            gload_lds16(Bsrc[1] + koff, nbuf + 16384 + 4096 + wave * 512);
        }
        asm volatile("s_barrier" ::: "memory");
        asm volatile("s_waitcnt lgkmcnt(0)" ::: "memory");
        __builtin_amdgcn_sched_barrier(0);
        __builtin_amdgcn_s_setprio(1);
        #pragma unroll
        for (int i = 0; i < 4; ++i)
            #pragma unroll
            for (int j = 0; j < 4; ++j)
                acc[i][j] = __builtin_amdgcn_mfma_f32_16x16x32_bf16(
                    af[i], bfr[j], acc[i][j], 0, 0, 0);
        __builtin_amdgcn_s_setprio(0);
        __builtin_amdgcn_sched_barrier(0);
        asm volatile("s_barrier" ::: "memory");

        // ---------- P3: i4..7, ks=1 ----------
        #pragma unroll
        for (int i = 0; i < 4; ++i) {
            int R = wm * 128 + (4 + i) * 16 + l16;
            af[i] = *(const bf16x8*)&sAc[(R * 8 + sw1) * 8];
        }
        if (pf) {
            gload_lds16(Bsrc[2] + koff, nbuf + 16384 + 2 * 4096 + wave * 512);
            gload_lds16(Bsrc[3] + koff, nbuf + 16384 + 3 * 4096 + wave * 512);
        }
        asm volatile("s_barrier" ::: "memory");
        asm volatile("s_waitcnt lgkmcnt(0)" ::: "memory");
        __builtin_amdgcn_sched_barrier(0);
        __builtin_amdgcn_s_setprio(1);
        #pragma unroll
        for (int i = 0; i < 4; ++i)
            #pragma unroll
            for (int j = 0; j < 4; ++j)
                acc[4 + i][j] = __builtin_amdgcn_mfma_f32_16x16x32_bf16(
                    af[i], bfr[j], acc[4 + i][j], 0, 0, 0);
        __builtin_amdgcn_s_setprio(0);
        __builtin_amdgcn_sched_barrier(0);
        // single per-tile drain: kt+1's 8 loads all issued; wait here (after
        // MFMA, before the trailing barrier) so next tile's reads are safe.
        asm volatile("s_waitcnt vmcnt(0)" ::: "memory");
        asm volatile("s_barrier" ::: "memory");
    }

    // epilogue
    #pragma unroll
    for (int i = 0; i < 8; ++i) {
        int rowb = m0 + wm * 128 + i * 16 + quad * 4;
        #pragma unroll
        for (int j = 0; j < 4; ++j) {
            int col = n0 + wn * 64 + j * 16 + l16;
            float bv = (EPI == 3) ? 0.f : bias[col];
            #pragma unroll
            for (int r = 0; r < 4; ++r) {
                float v = acc[i][j][r] + bv;
                if (EPI == 2) {                        // ReLU, bf16
                    v = v > 0.f ? v : 0.f;
                    ((u16*)outv)[(size_t)(rowb + r) * N + col] = f2bf(v);
                } else {                               // partial, bf16
                    ((u16*)outv)[((size_t)s * M + rowb + r) * N + col] = f2bf(v);
                }
            }
        }
    }
}

// ---------------------------------------------------------------------------
// Fused split-K reduce + LayerNorm. One block per row.
// ---------------------------------------------------------------------------
template <int KS, int RF32, int OF32>
__global__ __launch_bounds__(256) void lnfuse_kernel(
    const u16* __restrict__ P, const float* __restrict__ bias,
    const void* __restrict__ resv,
    const float* __restrict__ ga, const float* __restrict__ gb,
    void* __restrict__ outv)
{
    __shared__ float red[8];
    const int tid  = threadIdx.x;
    const int lane = tid & 63;
    const int wave = tid >> 6;
    const size_t row = blockIdx.x;
    const size_t SL  = (size_t)MROWS * D_MODEL;
    const int c = tid * 4;

    float v0, v1, v2, v3;
    {
        float4 bv = *(const float4*)(bias + c);
        v0 = bv.x; v1 = bv.y; v2 = bv.z; v3 = bv.w;
    }
    #pragma unroll
    for (int s = 0; s < KS; ++s) {
        uint2 p = *(const uint2*)(P + s * SL + row * D_MODEL + c);
        v0 += bf2f((u16)p.x); v1 += bf2f((u16)(p.x >> 16));
        v2 += bf2f((u16)p.y); v3 += bf2f((u16)(p.y >> 16));
    }
    if (RF32) {
        float4 r = *(const float4*)((const float*)resv + row * D_MODEL + c);
        v0 += r.x; v1 += r.y; v2 += r.z; v3 += r.w;
    } else {
        uint2 r = *(const uint2*)((const u16*)resv + row * D_MODEL + c);
        v0 += bf2f((u16)r.x); v1 += bf2f((u16)(r.x >> 16));
        v2 += bf2f((u16)r.y); v3 += bf2f((u16)(r.y >> 16));
    }

    float s_ = v0 + v1 + v2 + v3;
    #pragma unroll
    for (int o = 32; o > 0; o >>= 1) s_ += __shfl_xor(s_, o, 64);
    if (lane == 0) red[wave] = s_;
    __syncthreads();
    float mean = (red[0] + red[1] + red[2] + red[3]) * (1.f / 1024.f);

    float d0 = v0 - mean, d1 = v1 - mean, d2 = v2 - mean, d3 = v3 - mean;
    float q = d0 * d0 + d1 * d1 + d2 * d2 + d3 * d3;
    #pragma unroll
    for (int o = 32; o > 0; o >>= 1) q += __shfl_xor(q, o, 64);
    if (lane == 0) red[4 + wave] = q;
    __syncthreads();
    float var = (red[4] + red[5] + red[6] + red[7]) * (1.f / 1023.f);
    float inv = 1.f / (sqrtf(var) + 1e-6f);

    float y0 = d0 * inv * ga[c + 0] + gb[c + 0];
    float y1 = d1 * inv * ga[c + 1] + gb[c + 1];
    float y2 = d2 * inv * ga[c + 2] + gb[c + 2];
    float y3 = d3 * inv * ga[c + 3] + gb[c + 3];
    if (OF32) {
        float4 y = {y0, y1, y2, y3};
        *(float4*)((float*)outv + row * D_MODEL + c) = y;
    } else {
        ushort4 y = {f2bf(y0), f2bf(y1), f2bf(y2), f2bf(y3)};
        *(ushort4*)((u16*)outv + row * D_MODEL + c) = y;
    }
}

// ---------------------------------------------------------------------------
// MFMA flash attention (causal) + FOLDED WEIGHT TRANSPOSES.
// 1024 independent single-q-tile blocks, XCD remap, balanced qt map
// (per-CU iteration sum == 66 for every CU). V arrives transposed
// (Vt[bh][d][l]); staging = 2 uint4 loads + 2 swizzled ds_write_b128.
// blocks [0,1024): attention; [1024,3328): Wo/W1/W2 64x64 transpose tiles.
// Softmax uses exp2 (Q pre-scaled by 0.125*log2e at QKV epilogue).
// ---------------------------------------------------------------------------
__global__ __launch_bounds__(256) void attn_kernel(
    const u16* __restrict__ Q, const u16* __restrict__ K,
    const u16* __restrict__ V, u16* __restrict__ out,
    const float* __restrict__ Wo, u16* __restrict__ Wot,
    const float* __restrict__ W1, u16* __restrict__ W1t,
    const float* __restrict__ W2, u16* __restrict__ W2t)
{
    __shared__ u16 smem[13824];   // 27648 B: ks|vs|ps for attn, tile for wt
    u16* ks = smem;                       // 64*72
    u16* vs = smem + 4608;                // 64*72
    u16* ps = smem + 9216;                // 4 waves * 16*72

    const int tid  = threadIdx.x;
    const int bi   = blockIdx.x;

    if (bi >= 1024) {   // ---- weight transpose blocks ----
        float* tile = (float*)smem;       // 64*65 floats = 16640 B
        int t = bi - 1024;
        if (t < 256)       wt_tile(Wo, Wot, 1024, 1024, t,        tid, tile);
        else if (t < 1280) wt_tile(W1, W1t, 1024, 4096, t - 256,  tid, tile);
        else               wt_tile(W2, W2t, 4096, 1024, t - 1280, tid, tile);
        return;
    }

    const int lane = tid & 63;
    const int wave = tid >> 6;
    const int l16  = lane & 15;
    const int quad = lane >> 4;

    // 8 XCDs x (4 heads x 32 q-tiles); balanced qt map (see header).
    const int xcd = bi & 7;
    const int idx = bi >> 3;            // 0..127
    const int bh  = xcd * 4 + (idx & 3);
    const int j   = idx >> 2;           // 0..31
    const int qt  = (j < 16) ? (31 - j) : (j - 16);
    const int b   = bh >> 4, h = bh & 15;
    const size_t head_off = (size_t)bh * LL * DH;

    const u16* Qh = Q + head_off;
    const u16* Kh = K + head_off;
    const u16* Vh = V + head_off;       // Vt layout: [d][l]

    const int base = qt * 64 + wave * 16;
    const int qg   = base + l16;

    const bf16x8 qf0 = *(const bf16x8*)&Qh[(size_t)qg * DH + quad * 8];
    const bf16x8 qf1 = *(const bf16x8*)&Qh[(size_t)qg * DH + 32 + quad * 8];

    float lsum = 0.f;
    f32x4 o[4];
    #pragma unroll
    for (int t = 0; t < 4; ++t) o[t] = (f32x4){0.f, 0.f, 0.f, 0.f};

    u16* psw = ps + wave * 1152;         // 16*72 per wave

    const int key = tid >> 2;            // 0..63 (K: key row; V: d row)
    const int kd0 = (tid & 3) * 16;      // 0,16,32,48 (K: d seg; V: key seg)

    // V swizzle constants (loop-invariant): vs32[d*36 + (kp ^ C)], C=4*((d>>3)&7)
    const int vC    = 4 * ((key >> 3) & 7);
    const int vbase = (kd0 >> 1) ^ (vC & 24);   // kp0 = kd0/2, 8-aligned run
    const int vofA  = vbase + (vC & 4);
    const int vofB  = vbase + ((vC & 4) ^ 4);
    u32* vs32 = (u32*)vs;

    uint4 kr0, kr1, vr0, vr1;
    {
        const u16* ksrc = Kh + (size_t)key * DH + kd0;
        kr0 = *(const uint4*)ksrc;
        kr1 = *(const uint4*)(ksrc + 8);
        const u16* vsrc = Vh + (size_t)key * LL + kd0;
        vr0 = *(const uint4*)vsrc;
        vr1 = *(const uint4*)(vsrc + 8);
    }

    for (int c = 0; c <= qt; ++c) {
        __syncthreads();
        *(uint4*)&ks[key * 72 + kd0]     = kr0;
        *(uint4*)&ks[key * 72 + kd0 + 8] = kr1;
        *(uint4*)&vs32[key * 36 + vofA]  = vr0;
        *(uint4*)&vs32[key * 36 + vofB]  = vr1;
        __syncthreads();
        if (c < qt) {
            const u16* ksrc = Kh + (size_t)((c + 1) * 64 + key) * DH + kd0;
            kr0 = *(const uint4*)ksrc;
            kr1 = *(const uint4*)(ksrc + 8);
            const u16* vsrc = Vh + (size_t)key * LL + (c + 1) * 64 + kd0;
            vr0 = *(const uint4*)vsrc;
            vr1 = *(const uint4*)(vsrc + 8);
        }

        f32x4 st[4];
        #pragma unroll
        for (int t = 0; t < 4; ++t) {
            bf16x8 k0 = *(const bf16x8*)&ks[(t * 16 + l16) * 72 + quad * 8];
            bf16x8 k1 = *(const bf16x8*)&ks[(t * 16 + l16) * 72 + 32 + quad * 8];
            f32x4 s = (f32x4){0.f, 0.f, 0.f, 0.f};
            s = __builtin_amdgcn_mfma_f32_16x16x32_bf16(k0, qf0, s, 0, 0, 0);
            s = __builtin_amdgcn_mfma_f32_16x16x32_bf16(k1, qf1, s, 0, 0, 0);
            st[t] = s;
        }

        if (c == qt) {
            #pragma unroll
            for (int t = 0; t < 4; ++t)
                #pragma unroll
                for (int r = 0; r < 4; ++r)
                    if (c * 64 + t * 16 + quad * 4 + r > qg) st[t][r] = -INFINITY;
        }

        {
            float psum = 0.f;
            #pragma unroll
            for (int t = 0; t < 4; ++t) {
                float p0 = exp2f(st[t][0]), p1 = exp2f(st[t][1]);
                float p2 = exp2f(st[t][2]), p3 = exp2f(st[t][3]);
                psum += (p0 + p1) + (p2 + p3);
                uint2 w = {pack_bf_trunc(p0, p1), pack_bf_trunc(p2, p3)};
                *(uint2*)&psw[l16 * 72 + t * 16 + quad * 4] = w;
            }
            psum += __shfl_xor(psum, 16, 64);
            psum += __shfl_xor(psum, 32, 64);
            lsum += psum;
        }

        bf16x8 pf0 = *(const bf16x8*)&psw[l16 * 72 + quad * 8];
        bf16x8 pf1 = *(const bf16x8*)&psw[l16 * 72 + 32 + quad * 8];

        #pragma unroll
        for (int dt = 0; dt < 4; ++dt) {
            int d  = dt * 16 + l16;
            int sw = 4 * ((d >> 3) & 7);
            bf16x8 vf0 = *(const bf16x8*)&vs[d * 72 + 2 * ((quad * 4) ^ sw)];
            bf16x8 vf1 = *(const bf16x8*)&vs[d * 72 + 2 * ((16 + quad * 4) ^ sw)];
            o[dt] = __builtin_amdgcn_mfma_f32_16x16x32_bf16(pf0, vf0, o[dt], 0, 0, 0);
            o[dt] = __builtin_amdgcn_mfma_f32_16x16x32_bf16(pf1, vf1, o[dt], 0, 0, 0);
        }
    }

    {
        float i0 = 1.f / __shfl(lsum, quad * 4 + 0, 64);
        float i1 = 1.f / __shfl(lsum, quad * 4 + 1, 64);
        float i2 = 1.f / __shfl(lsum, quad * 4 + 2, 64);
        float i3 = 1.f / __shfl(lsum, quad * 4 + 3, 64);
        #pragma unroll
        for (int dt = 0; dt < 4; ++dt) {
            size_t col = h * DH + dt * 16 + l16;
            size_t r0  = ((size_t)b * LL + base + quad * 4) * D_MODEL + col;
            out[r0]               = f2bf(o[dt][0] * i0);
            out[r0 + D_MODEL]     = f2bf(o[dt][1] * i1);
            out[r0 + 2 * D_MODEL] = f2bf(o[dt][2] * i2);
            out[r0 + 3 * D_MODEL] = f2bf(o[dt][3] * i3);
        }
    }
}

// ---------------------------------------------------------------------------
extern "C" void kernel_launch(void* const* d_in, const int* in_sizes, int n_in,
                              void* d_out, int out_size, void* d_ws, size_t ws_size,
                              hipStream_t stream)
{
    const float* x    = (const float*)d_in[0];
    // d_in[1] = mask (int32) — causal, handled analytically
    const float* Wqkv = (const float*)d_in[2];
    const float* bqkv = (const float*)d_in[3];
    const float* Wo   = (const float*)d_in[4];
    const float* bo   = (const float*)d_in[5];
    const float* W1   = (const float*)d_in[6];
    const float* b1   = (const float*)d_in[7];
    const float* W2   = (const float*)d_in[8];
    const float* b2   = (const float*)d_in[9];
    const float* ln1a = (const float*)d_in[10];
    const float* ln1b = (const float*)d_in[11];
    const float* ln2a = (const float*)d_in[12];
    const float* ln2b = (const float*)d_in[13];

    char* ws = (char*)d_ws;
    const size_t HSZ = (size_t)BB * NH * LL * DH;      // 4,194,304 elems
    u16*   Qp    = (u16*)ws;
    u16*   Kp    = Qp + HSZ;
    u16*   Vp    = Kp + HSZ;                               // Vt[bh][d][l]
    u16*   attn  = Vp + HSZ;
    u16*   hbuf  = (u16*)ws;                               // alias (QKV/attn dead)
    u16*   xb    = (u16*)(ws + 33554432);                  // bf16 x, 8 MB
    u16*   x1    = (u16*)(ws + 50331648);                  // bf16, 8 MB
    u16*   Wqkvt = (u16*)(ws + 58720256);                  // 3072x1024 bf16
    u16*   Wot   = (u16*)(ws + 65011712);                  // 1024x1024 bf16
    u16*   W1t   = (u16*)(ws + 67108864);                  // 4096x1024 bf16
    u16*   W2t   = (u16*)(ws + 75497472);                  // 1024x4096 bf16
    u16*   Pbuf  = (u16*)(ws + 83886080);                  // up to 4x 4096x1024 bf16

    dim3 blk(256);

    // 0) prep: x->bf16 + Wqkv transpose (only what QKV GEMM needs)
    prep_kernel<<<dim3(2816), blk, 0, stream>>>(x, xb, Wqkv, Wqkvt);

    // 1) qkv = x @ Wqkv + bqkv -> scatter Q(*0.125*log2e), K, Vt (bf16)
    gemm_bt_kernel<0,0,0,1><<<dim3(24, 32), blk, 0, stream>>>(
        xb, Wqkvt, bqkv, nullptr, Qp, Kp, Vp, MROWS, 3 * D_MODEL, D_MODEL);
    // 2) attention -> attn bf16; folds Wo/W1/W2 transposes into idle slots
    attn_kernel<<<dim3(3328), blk, 0, stream>>>(
        Qp, Kp, Vp, attn, Wo, Wot, W1, W1t, W2, W2t);
    // 3) Wo partials (split-K=2)
    gemm_bt_kernel<3,0,0,2><<<dim3(8, 64), blk, 0, stream>>>(
        attn, Wot, bo, nullptr, Pbuf, nullptr, nullptr, MROWS, D_MODEL, D_MODEL);
    // 4) x1 = LN1(sum(P) + bo + x)  (fused reduce+LN, bf16 out)
    lnfuse_kernel<2,1,0><<<dim3(MROWS), blk, 0, stream>>>(
        Pbuf, bo, x, ln1a, ln1b, x1);
    // 5) h = relu(x1 @ W1 + b1)  (bf16 out) — 256^2 4-phase kernel
    gemm256_kernel<2,1><<<dim3(16, 16), dim3(512), 0, stream>>>(
        x1, W1t, b1, hbuf, MROWS, D_FFN, D_MODEL);
    // 6) W2 partials (split-K=4) — 256^2 4-phase kernel
    gemm256_kernel<3,4><<<dim3(4, 64), dim3(512), 0, stream>>>(
        hbuf, W2t, nullptr, Pbuf, MROWS, D_MODEL, D_FFN);
    // 7) out = LN2(sum(P) + b2 + x1)  (fused reduce+LN, fp32 out)
    lnfuse_kernel<4,0,1><<<dim3(MROWS), blk, 0, stream>>>(
        Pbuf, b2, x1, ln2a, ln2b, d_out);
}

// Round 12
// 320.546 us; speedup vs baseline: 1.0083x; 1.0083x over previous
//
#include <hip/hip_runtime.h>

#define D_MODEL 1024
#define D_FFN   4096
#define NH      16
#define DH      64
#define BB      2
#define LL      2048
#define MROWS   (BB * LL)   // 4096

typedef unsigned short u16;
typedef unsigned int   u32;
typedef short bf16x8 __attribute__((ext_vector_type(8)));
typedef float f32x4  __attribute__((ext_vector_type(4)));

__device__ __forceinline__ float bf2f(u16 u) {
    union { u32 i; float f; } v;
    v.i = ((u32)u) << 16;
    return v.f;
}
__device__ __forceinline__ u16 f2bf(float f) {
    union { float f; u32 i; } v;
    v.f = f;
    u32 x = v.i;
    x += 0x7fffu + ((x >> 16) & 1u);   // round to nearest even
    return (u16)(x >> 16);
}
// pack high-16s of two floats (truncating bf16): {lo=a, hi=b}
__device__ __forceinline__ u32 pack_bf_trunc(float a, float b) {
    return __builtin_amdgcn_perm(__float_as_uint(b), __float_as_uint(a),
                                 0x07060302u);
}

// async global->LDS, 16B per lane; ldsptr must be wave-uniform (HW adds lane*16)
typedef const __attribute__((address_space(1))) u32 gu32;
typedef __attribute__((address_space(3))) u32 lu32;
__device__ __forceinline__ void gload_lds16(const void* g, void* l) {
    __builtin_amdgcn_global_load_lds((gu32*)g, (lu32*)l, 16, 0, 0);
}

// ---------------------------------------------------------------------------
// 64x64 fp32->bf16 transpose tile helper (LDS tile passed in)
// ---------------------------------------------------------------------------
__device__ __forceinline__ void wt_tile(
    const float* __restrict__ W, u16* __restrict__ Wt,
    int K, int N, int t, int tid, float* tile /* 64*65 floats */)
{
    const int ntiles = N >> 6;
    const int n0 = (t % ntiles) * 64;
    const int k0 = (t / ntiles) * 64;

    int kr = tid >> 4;             // 0..15
    int nc = (tid & 15) * 4;       // 0..60
    #pragma unroll
    for (int p = 0; p < 4; ++p) {
        float4 v = *(const float4*)&W[(size_t)(k0 + kr + p * 16) * N + n0 + nc];
        tile[(kr + p * 16) * 65 + nc + 0] = v.x;
        tile[(kr + p * 16) * 65 + nc + 1] = v.y;
        tile[(kr + p * 16) * 65 + nc + 2] = v.z;
        tile[(kr + p * 16) * 65 + nc + 3] = v.w;
    }
    __syncthreads();

    int nr = tid >> 2;             // 0..63
    int kc = (tid & 3) * 16;       // 0..48
    u16 o[16];
    #pragma unroll
    for (int j = 0; j < 16; ++j) o[j] = f2bf(tile[(kc + j) * 65 + nr]);
    u16* dst = &Wt[(size_t)(n0 + nr) * K + k0 + kc];
    *(uint4*)dst       = *(const uint4*)&o[0];
    *(uint4*)(dst + 8) = *(const uint4*)&o[8];
}

// ---------------------------------------------------------------------------
// Prep: blocks [0,2048) convert x fp32->bf16; [2048,2816) transpose Wqkv.
// ---------------------------------------------------------------------------
__global__ __launch_bounds__(256) void prep_kernel(
    const float* __restrict__ x,    u16* __restrict__ xb,
    const float* __restrict__ Wqkv, u16* __restrict__ Wqkvt)
{
    __shared__ float tile[64 * 65];
    const int tid = threadIdx.x;
    const int bi  = blockIdx.x;

    if (bi < 2048) {   // x convert
        int i = bi * 2048 + tid * 8;
        float4 a = *(const float4*)(x + i);
        float4 b = *(const float4*)(x + i + 4);
        u16 o[8] = {f2bf(a.x), f2bf(a.y), f2bf(a.z), f2bf(a.w),
                    f2bf(b.x), f2bf(b.y), f2bf(b.z), f2bf(b.w)};
        *(uint4*)(xb + i) = *(const uint4*)o;
        return;
    }
    wt_tile(Wqkv, Wqkvt, 1024, 3072, bi - 2048, tid, tile);
}

// ---------------------------------------------------------------------------
// MFMA bf16 GEMM, m97-style, XCD remap, optional split-K. Kept for QKV
// (scatter + V-transpose epilogue) and Wo (small, split-K=2).
// ---------------------------------------------------------------------------
template <int EPI, int RF32, int OF32, int KS>
__global__ __launch_bounds__(256, 4) void gemm_bt_kernel(
    const u16* __restrict__ A, const u16* __restrict__ Bt,
    const float* __restrict__ bias, const void* __restrict__ resv,
    void* __restrict__ out0v, u16* __restrict__ out1, u16* __restrict__ out2,
    int M, int N, int K)
{
    __shared__ u16 smem[16384];    // 32 KB: sA|sB staging; V-transpose tile
    u16* sA = smem;                // 128*64
    u16* sB = smem + 8192;         // 128*64

    const int tid  = threadIdx.x;
    const int lane = tid & 63;
    const int wave = tid >> 6;
    const int wm   = (wave & 1) * 64;
    const int wn   = (wave >> 1) * 64;
    const int quad = lane >> 4;
    const int l16  = lane & 15;

    // XCD-locality remap (requires gridDim.x % 2 == 0, gridDim.y % 4 == 0)
    const int nb  = gridDim.x;
    const int mb  = gridDim.y;
    const int f   = blockIdx.y * nb + blockIdx.x;   // dispatch-linear id
    const int xcd = f & 7;
    const int idx = f >> 3;
    const int rn  = nb >> 1;                        // region width  (tiles)
    const int rm  = mb >> 2;                        // region height (tiles)
    const int n0  = ((xcd & 1) * rn + (idx % rn)) * 128;
    const int ym  = (xcd >> 1) * rm + (idx / rn);   // 0..mb-1

    int s, m0;
    if (KS > 1) {
        const int mt = mb / KS;
        s  = ym / mt;
        m0 = (ym % mt) * 128;
    } else {
        s  = 0;
        m0 = ym * 128;
    }
    const int Kseg = K / KS;
    const int kbeg = s * Kseg;

    f32x4 acc[4][4];
    #pragma unroll
    for (int i = 0; i < 4; ++i)
        #pragma unroll
        for (int j = 0; j < 4; ++j)
            acc[i][j] = (f32x4){0.f, 0.f, 0.f, 0.f};

    const u16* Ablk = A  + (size_t)m0 * K;
    const u16* Bblk = Bt + (size_t)n0 * K;

    for (int k0 = kbeg; k0 < kbeg + Kseg; k0 += 64) {
        #pragma unroll
        for (int i = 0; i < 4; ++i) {
            int chunk = (i * 4 + wave) * 64 + lane;        // 0..1023
            int r = chunk >> 3;                            // row 0..127
            int c = (chunk & 7) ^ (r & 7);                 // swizzled k-chunk
            size_t goff = (size_t)r * K + k0 + c * 8;
            gload_lds16(Ablk + goff, &sA[(i * 4 + wave) * 512]);
            gload_lds16(Bblk + goff, &sB[(i * 4 + wave) * 512]);
        }
        __syncthreads();

        #pragma unroll
        for (int ks = 0; ks < 2; ++ks) {
            bf16x8 af[4], bfr[4];
            #pragma unroll
            for (int i = 0; i < 4; ++i) {
                int R = wm + i * 16 + l16;
                int slot = R * 8 + ((ks * 4 + quad) ^ (R & 7));
                af[i] = *(const bf16x8*)&sA[slot * 8];
            }
            #pragma unroll
            for (int j = 0; j < 4; ++j) {
                int R = wn + j * 16 + l16;
                int slot = R * 8 + ((ks * 4 + quad) ^ (R & 7));
                bfr[j] = *(const bf16x8*)&sB[slot * 8];
            }
            #pragma unroll
            for (int i = 0; i < 4; ++i)
                #pragma unroll
                for (int j = 0; j < 4; ++j)
                    acc[i][j] = __builtin_amdgcn_mfma_f32_16x16x32_bf16(
                        af[i], bfr[j], acc[i][j], 0, 0, 0);
        }
        __syncthreads();
    }

    // --- V-transpose epilogue (EPI 0, V columns): write Vt[bh][d][l] ---
    if (EPI == 0 && n0 >= 2 * D_MODEL) {
        u16* tile = smem;                       // 128x128 u16 = 32 KB
        #pragma unroll
        for (int i = 0; i < 4; ++i) {
            int rl = wm + i * 16 + quad * 4;    // local row (l) base
            #pragma unroll
            for (int j = 0; j < 4; ++j) {
                int cl = wn + j * 16 + l16;     // local col (d)
                float bv = bias[n0 + cl];
                int sx = 8 * (cl & 15);         // XOR swizzle (8-aligned)
                #pragma unroll
                for (int r = 0; r < 4; ++r)
                    tile[cl * 128 + ((rl + r) ^ sx)] = f2bf(acc[i][j][r] + bv);
            }
        }
        __syncthreads();
        int cl  = tid >> 1;                     // local col 0..127
        int rb  = (tid & 1) * 64;               // row half
        int col = n0 + cl;
        int h   = (col >> 6) & 15;
        int d   = col & 63;
        int b   = m0 >> 11;
        int l0  = (m0 & 2047) + rb;
        int sx  = 8 * (cl & 15);
        u16* dst = out2 + ((size_t)(b * NH + h) * DH + d) * LL + l0;
        #pragma unroll
        for (int u = 0; u < 8; ++u) {
            uint4 q = *(const uint4*)&tile[cl * 128 + ((rb + 8 * u) ^ sx)];
            *(uint4*)(dst + 8 * u) = q;
        }
        return;
    }

    #pragma unroll
    for (int i = 0; i < 4; ++i) {
        int rowb = m0 + wm + i * 16 + quad * 4;
        #pragma unroll
        for (int j = 0; j < 4; ++j) {
            int col = n0 + wn + j * 16 + l16;
            float bv = (EPI == 3) ? 0.f : bias[col];
            #pragma unroll
            for (int r = 0; r < 4; ++r) {
                int rr = rowb + r;
                float v = acc[i][j][r] + bv;
                if (EPI == 0) {
                    int h     = (col >> 6) & 15;
                    int d     = col & 63;
                    int b     = rr >> 11;
                    int l     = rr & 2047;
                    size_t idx2 = ((size_t)(b * NH + h) * LL + l) * DH + d;
                    u16* o0 = (u16*)out0v;
                    // Q pre-scaled by 0.125 * log2(e) so attention can use
                    // exp2 directly (softmax is scale-consistent).
                    if (col < D_MODEL)  o0[idx2]   = f2bf(v * 0.18033688f);
                    else                out1[idx2] = f2bf(v);
                } else if (EPI == 3) {
                    ((u16*)out0v)[((size_t)s * M + rr) * N + col] = f2bf(v);
                } else {
                    size_t idx2 = (size_t)rr * N + col;
                    if (EPI == 1) {
                        v += RF32 ? ((const float*)resv)[idx2]
                                  : bf2f(((const u16*)resv)[idx2]);
                    } else {  // EPI == 2: ReLU
                        v = v > 0.f ? v : 0.f;
                    }
                    if (OF32) ((float*)out0v)[idx2] = v;
                    else      ((u16*)out0v)[idx2]   = f2bf(v);
                }
            }
        }
    }
}

// ---------------------------------------------------------------------------
// R12: 256x256 GEMM, BK=32, 3-BUFFER 2-TILE-DEEP COUNTED PIPELINE (T4 proper).
// R6 (1-phase drain0) and R11 (4-phase drain0) were both the drain-0 quadrant
// m218 documents as null: the once-per-tile vmcnt(0) exposed ~700cy of HBM
// latency. This version never drains mid-loop:
//   iter kt: STAGE(kt+2 -> buf[(kt+2)%3])   // 4 loads/thread (2 A + 2 B)
//            s_waitcnt vmcnt(8)             // kt+1's 4 + kt+2's 4 stay in
//                                           // flight; kt's (issued 2 tiles
//                                           // ago, ~900cy cover) landed
//            s_barrier
//            12 ds_read_b128 + lgkmcnt(0) + sched_barrier (rule #18)
//            setprio(1) 32 MFMA setprio(0)
//            s_barrier                      // reads done: next iter may
//                                           // stage into buf[(kt+3)%3]==kt%3
// Epilogue waits: vmcnt(4) at kt==NT-2, vmcnt(0) at kt==NT-1.
// LDS 96 KB = 3 x [A 256x32 | B 256x32] bf16. Swizzle: 4 chunks/row,
// c = (L&3)^(r&3) on both the pre-swizzled global source and the ds_read
// slot (rule #21). 512 thr = 8 waves (2M x 4N), per-wave 128x64 out.
// EPI 2: relu+bias bf16. EPI 3: bf16 partial. Grids: FFN1 (16,16); W2 (4,64).
// ---------------------------------------------------------------------------
template <int EPI, int KS>
__global__ __launch_bounds__(512, 2) void gemm256_kernel(
    const u16* __restrict__ A, const u16* __restrict__ Bt,
    const float* __restrict__ bias, void* __restrict__ outv,
    int M, int N, int K)
{
    __shared__ u16 dsm[49152];     // 96 KB: 3 bufs x [A 8192 | B 8192] u16

    const int tid  = threadIdx.x;
    const int lane = tid & 63;
    const int wave = tid >> 6;
    const int wm   = wave >> 2;            // 0..1  (M half)
    const int wn   = wave & 3;             // 0..3  (N quarter)
    const int quad = lane >> 4;
    const int l16  = lane & 15;

    // XCD-locality remap (nb % 2 == 0, mb % 4 == 0)
    const int nb  = gridDim.x;
    const int mb  = gridDim.y;
    const int f   = blockIdx.y * nb + blockIdx.x;
    const int xcd = f & 7;
    const int idx = f >> 3;
    const int rn  = nb >> 1;
    const int rm  = mb >> 2;
    const int n0  = ((xcd & 1) * rn + (idx % rn)) * 256;
    const int ym  = (xcd >> 1) * rm + (idx / rn);

    int s, m0;
    if (KS > 1) {
        const int mt = mb / KS;
        s  = ym / mt;
        m0 = (ym % mt) * 256;
    } else {
        s  = 0;
        m0 = ym * 256;
    }
    const int Kseg = K / KS;
    const int kbeg = s * Kseg;
    const int NT   = Kseg >> 5;            // BK=32 -> 32 tiles per call site

    // staging: per matrix, thread stages chunks L = q*512+tid (q=0,1);
    // r = L>>2 = q*128 + (tid>>2), LDS col cl = L&3 = tid&3, global col
    // c = cl ^ (r&3) = (tid&3) ^ ((tid>>2)&3)  (q*128 % 4 == 0).
    const int rr2 = tid >> 2;              // 0..127
    const int cc  = ((tid & 3) ^ (rr2 & 3)) * 8;   // element offset
    const u16* Asrc[2];
    const u16* Bsrc[2];
    #pragma unroll
    for (int q = 0; q < 2; ++q) {
        Asrc[q] = A  + (size_t)(m0 + q * 128 + rr2) * K + kbeg + cc;
        Bsrc[q] = Bt + (size_t)(n0 + q * 128 + rr2) * K + kbeg + cc;
    }

    f32x4 acc[8][4];
    #pragma unroll
    for (int i = 0; i < 8; ++i)
        #pragma unroll
        for (int j = 0; j < 4; ++j)
            acc[i][j] = (f32x4){0.f, 0.f, 0.f, 0.f};

    // stage tile t into buffer b (4 gloads/thread: A q0,q1 then B q0,q1)
    auto STAGE = [&](int t, int b) {
        const int koff = t * 32;
        u16* bb = &dsm[b * 16384];
        #pragma unroll
        for (int q = 0; q < 2; ++q)
            gload_lds16(Asrc[q] + koff, bb + q * 4096 + wave * 512);
        #pragma unroll
        for (int q = 0; q < 2; ++q)
            gload_lds16(Bsrc[q] + koff, bb + 8192 + q * 4096 + wave * 512);
    };

    // prologue: tiles 0 and 1 into bufs 0 and 1
    STAGE(0, 0);
    STAGE(1, 1);

    int bc = 0;                            // compute buffer = kt % 3
    int bs = 2;                            // stage buffer   = (kt+2) % 3
    #pragma unroll 1
    for (int kt = 0; kt < NT; ++kt) {
        if (kt + 2 < NT) {
            STAGE(kt + 2, bs);
            asm volatile("s_waitcnt vmcnt(8)" ::: "memory");
        } else if (kt + 1 < NT) {
            asm volatile("s_waitcnt vmcnt(4)" ::: "memory");
        } else {
            asm volatile("s_waitcnt vmcnt(0)" ::: "memory");
        }
        asm volatile("s_barrier" ::: "memory");        // tile kt readable

        const u16* sAc = &dsm[bc * 16384];
        const u16* sBc = sAc + 8192;
        bf16x8 af[8], bfr[4];
        #pragma unroll
        for (int i = 0; i < 8; ++i) {
            int R = wm * 128 + i * 16 + l16;
            af[i] = *(const bf16x8*)&sAc[(R * 4 + (quad ^ (R & 3))) * 8];
        }
        #pragma unroll
        for (int j = 0; j < 4; ++j) {
            int R = wn * 64 + j * 16 + l16;
            bfr[j] = *(const bf16x8*)&sBc[(R * 4 + (quad ^ (R & 3))) * 8];
        }
        asm volatile("s_waitcnt lgkmcnt(0)" ::: "memory");
        __builtin_amdgcn_sched_barrier(0);
        __builtin_amdgcn_s_setprio(1);
        #pragma unroll
        for (int i = 0; i < 8; ++i)
            #pragma unroll
            for (int j = 0; j < 4; ++j)
                acc[i][j] = __builtin_amdgcn_mfma_f32_16x16x32_bf16(
                    af[i], bfr[j], acc[i][j], 0, 0, 0);
        __builtin_amdgcn_s_setprio(0);
        __builtin_amdgcn_sched_barrier(0);
        asm volatile("s_barrier" ::: "memory");        // reads done; buf bc
                                                       // reusable next iter
        bc = (bc == 2) ? 0 : bc + 1;
        bs = (bs == 2) ? 0 : bs + 1;
    }

    // epilogue
    #pragma unroll
    for (int i = 0; i < 8; ++i) {
        int rowb = m0 + wm * 128 + i * 16 + quad * 4;
        #pragma unroll
        for (int j = 0; j < 4; ++j) {
            int col = n0 + wn * 64 + j * 16 + l16;
            float bv = (EPI == 3) ? 0.f : bias[col];
            #pragma unroll
            for (int r = 0; r < 4; ++r) {
                float v = acc[i][j][r] + bv;
                if (EPI == 2) {                        // ReLU, bf16
                    v = v > 0.f ? v : 0.f;
                    ((u16*)outv)[(size_t)(rowb + r) * N + col] = f2bf(v);
                } else {                               // partial, bf16
                    ((u16*)outv)[((size_t)s * M + rowb + r) * N + col] = f2bf(v);
                }
            }
        }
    }
}

// ---------------------------------------------------------------------------
// Fused split-K reduce + LayerNorm. One block per row.
// ---------------------------------------------------------------------------
template <int KS, int RF32, int OF32>
__global__ __launch_bounds__(256) void lnfuse_kernel(
    const u16* __restrict__ P, const float* __restrict__ bias,
    const void* __restrict__ resv,
    const float* __restrict__ ga, const float* __restrict__ gb,
    void* __restrict__ outv)
{
    __shared__ float red[8];
    const int tid  = threadIdx.x;
    const int lane = tid & 63;
    const int wave = tid >> 6;
    const size_t row = blockIdx.x;
    const size_t SL  = (size_t)MROWS * D_MODEL;
    const int c = tid * 4;

    float v0, v1, v2, v3;
    {
        float4 bv = *(const float4*)(bias + c);
        v0 = bv.x; v1 = bv.y; v2 = bv.z; v3 = bv.w;
    }
    #pragma unroll
    for (int s = 0; s < KS; ++s) {
        uint2 p = *(const uint2*)(P + s * SL + row * D_MODEL + c);
        v0 += bf2f((u16)p.x); v1 += bf2f((u16)(p.x >> 16));
        v2 += bf2f((u16)p.y); v3 += bf2f((u16)(p.y >> 16));
    }
    if (RF32) {
        float4 r = *(const float4*)((const float*)resv + row * D_MODEL + c);
        v0 += r.x; v1 += r.y; v2 += r.z; v3 += r.w;
    } else {
        uint2 r = *(const uint2*)((const u16*)resv + row * D_MODEL + c);
        v0 += bf2f((u16)r.x); v1 += bf2f((u16)(r.x >> 16));
        v2 += bf2f((u16)r.y); v3 += bf2f((u16)(r.y >> 16));
    }

    float s_ = v0 + v1 + v2 + v3;
    #pragma unroll
    for (int o = 32; o > 0; o >>= 1) s_ += __shfl_xor(s_, o, 64);
    if (lane == 0) red[wave] = s_;
    __syncthreads();
    float mean = (red[0] + red[1] + red[2] + red[3]) * (1.f / 1024.f);

    float d0 = v0 - mean, d1 = v1 - mean, d2 = v2 - mean, d3 = v3 - mean;
    float q = d0 * d0 + d1 * d1 + d2 * d2 + d3 * d3;
    #pragma unroll
    for (int o = 32; o > 0; o >>= 1) q += __shfl_xor(q, o, 64);
    if (lane == 0) red[4 + wave] = q;
    __syncthreads();
    float var = (red[4] + red[5] + red[6] + red[7]) * (1.f / 1023.f);
    float inv = 1.f / (sqrtf(var) + 1e-6f);

    float y0 = d0 * inv * ga[c + 0] + gb[c + 0];
    float y1 = d1 * inv * ga[c + 1] + gb[c + 1];
    float y2 = d2 * inv * ga[c + 2] + gb[c + 2];
    float y3 = d3 * inv * ga[c + 3] + gb[c + 3];
    if (OF32) {
        float4 y = {y0, y1, y2, y3};
        *(float4*)((float*)outv + row * D_MODEL + c) = y;
    } else {
        ushort4 y = {f2bf(y0), f2bf(y1), f2bf(y2), f2bf(y3)};
        *(ushort4*)((u16*)outv + row * D_MODEL + c) = y;
    }
}

// ---------------------------------------------------------------------------
// MFMA flash attention (causal) + FOLDED WEIGHT TRANSPOSES.
// 1024 independent single-q-tile blocks, XCD remap, balanced qt map
// (per-CU iteration sum == 66 for every CU). V arrives transposed
// (Vt[bh][d][l]); staging = 2 uint4 loads + 2 swizzled ds_write_b128.
// blocks [0,1024): attention; [1024,3328): Wo/W1/W2 64x64 transpose tiles.
// Softmax uses exp2 (Q pre-scaled by 0.125*log2e at QKV epilogue).
// ---------------------------------------------------------------------------
__global__ __launch_bounds__(256) void attn_kernel(
    const u16* __restrict__ Q, const u16* __restrict__ K,
    const u16* __restrict__ V, u16* __restrict__ out,
    const float* __restrict__ Wo, u16* __restrict__ Wot,
    const float* __restrict__ W1, u16* __restrict__ W1t,
    const float* __restrict__ W2, u16* __restrict__ W2t)
{
    __shared__ u16 smem[13824];   // 27648 B: ks|vs|ps for attn, tile for wt
    u16* ks = smem;                       // 64*72
    u16* vs = smem + 4608;                // 64*72
    u16* ps = smem + 9216;                // 4 waves * 16*72

    const int tid  = threadIdx.x;
    const int bi   = blockIdx.x;

    if (bi >= 1024) {   // ---- weight transpose blocks ----
        float* tile = (float*)smem;       // 64*65 floats = 16640 B
        int t = bi - 1024;
        if (t < 256)       wt_tile(Wo, Wot, 1024, 1024, t,        tid, tile);
        else if (t < 1280) wt_tile(W1, W1t, 1024, 4096, t - 256,  tid, tile);
        else               wt_tile(W2, W2t, 4096, 1024, t - 1280, tid, tile);
        return;
    }

    const int lane = tid & 63;
    const int wave = tid >> 6;
    const int l16  = lane & 15;
    const int quad = lane >> 4;

    // 8 XCDs x (4 heads x 32 q-tiles); balanced qt map (see header).
    const int xcd = bi & 7;
    const int idx = bi >> 3;            // 0..127
    const int bh  = xcd * 4 + (idx & 3);
    const int j   = idx >> 2;           // 0..31
    const int qt  = (j < 16) ? (31 - j) : (j - 16);
    const int b   = bh >> 4, h = bh & 15;
    const size_t head_off = (size_t)bh * LL * DH;

    const u16* Qh = Q + head_off;
    const u16* Kh = K + head_off;
    const u16* Vh = V + head_off;       // Vt layout: [d][l]

    const int base = qt * 64 + wave * 16;
    const int qg   = base + l16;

    const bf16x8 qf0 = *(const bf16x8*)&Qh[(size_t)qg * DH + quad * 8];
    const bf16x8 qf1 = *(const bf16x8*)&Qh[(size_t)qg * DH + 32 + quad * 8];

    float lsum = 0.f;
    f32x4 o[4];
    #pragma unroll
    for (int t = 0; t < 4; ++t) o[t] = (f32x4){0.f, 0.f, 0.f, 0.f};

    u16* psw = ps + wave * 1152;         // 16*72 per wave

    const int key = tid >> 2;            // 0..63 (K: key row; V: d row)
    const int kd0 = (tid & 3) * 16;      // 0,16,32,48 (K: d seg; V: key seg)

    // V swizzle constants (loop-invariant): vs32[d*36 + (kp ^ C)], C=4*((d>>3)&7)
    const int vC    = 4 * ((key >> 3) & 7);
    const int vbase = (kd0 >> 1) ^ (vC & 24);   // kp0 = kd0/2, 8-aligned run
    const int vofA  = vbase + (vC & 4);
    const int vofB  = vbase + ((vC & 4) ^ 4);
    u32* vs32 = (u32*)vs;

    uint4 kr0, kr1, vr0, vr1;
    {
        const u16* ksrc = Kh + (size_t)key * DH + kd0;
        kr0 = *(const uint4*)ksrc;
        kr1 = *(const uint4*)(ksrc + 8);
        const u16* vsrc = Vh + (size_t)key * LL + kd0;
        vr0 = *(const uint4*)vsrc;
        vr1 = *(const uint4*)(vsrc + 8);
    }

    for (int c = 0; c <= qt; ++c) {
        __syncthreads();
        *(uint4*)&ks[key * 72 + kd0]     = kr0;
        *(uint4*)&ks[key * 72 + kd0 + 8] = kr1;
        *(uint4*)&vs32[key * 36 + vofA]  = vr0;
        *(uint4*)&vs32[key * 36 + vofB]  = vr1;
        __syncthreads();
        if (c < qt) {
            const u16* ksrc = Kh + (size_t)((c + 1) * 64 + key) * DH + kd0;
            kr0 = *(const uint4*)ksrc;
            kr1 = *(const uint4*)(ksrc + 8);
            const u16* vsrc = Vh + (size_t)key * LL + (c + 1) * 64 + kd0;
            vr0 = *(const uint4*)vsrc;
            vr1 = *(const uint4*)(vsrc + 8);
        }

        f32x4 st[4];
        #pragma unroll
        for (int t = 0; t < 4; ++t) {
            bf16x8 k0 = *(const bf16x8*)&ks[(t * 16 + l16) * 72 + quad * 8];
            bf16x8 k1 = *(const bf16x8*)&ks[(t * 16 + l16) * 72 + 32 + quad * 8];
            f32x4 s = (f32x4){0.f, 0.f, 0.f, 0.f};
            s = __builtin_amdgcn_mfma_f32_16x16x32_bf16(k0, qf0, s, 0, 0, 0);
            s = __builtin_amdgcn_mfma_f32_16x16x32_bf16(k1, qf1, s, 0, 0, 0);
            st[t] = s;
        }

        if (c == qt) {
            #pragma unroll
            for (int t = 0; t < 4; ++t)
                #pragma unroll
                for (int r = 0; r < 4; ++r)
                    if (c * 64 + t * 16 + quad * 4 + r > qg) st[t][r] = -INFINITY;
        }

        {
            float psum = 0.f;
            #pragma unroll
            for (int t = 0; t < 4; ++t) {
                float p0 = exp2f(st[t][0]), p1 = exp2f(st[t][1]);
                float p2 = exp2f(st[t][2]), p3 = exp2f(st[t][3]);
                psum += (p0 + p1) + (p2 + p3);
                uint2 w = {pack_bf_trunc(p0, p1), pack_bf_trunc(p2, p3)};
                *(uint2*)&psw[l16 * 72 + t * 16 + quad * 4] = w;
            }
            psum += __shfl_xor(psum, 16, 64);
            psum += __shfl_xor(psum, 32, 64);
            lsum += psum;
        }

        bf16x8 pf0 = *(const bf16x8*)&psw[l16 * 72 + quad * 8];
        bf16x8 pf1 = *(const bf16x8*)&psw[l16 * 72 + 32 + quad * 8];

        #pragma unroll
        for (int dt = 0; dt < 4; ++dt) {
            int d  = dt * 16 + l16;
            int sw = 4 * ((d >> 3) & 7);
            bf16x8 vf0 = *(const bf16x8*)&vs[d * 72 + 2 * ((quad * 4) ^ sw)];
            bf16x8 vf1 = *(const bf16x8*)&vs[d * 72 + 2 * ((16 + quad * 4) ^ sw)];
            o[dt] = __builtin_amdgcn_mfma_f32_16x16x32_bf16(pf0, vf0, o[dt], 0, 0, 0);
            o[dt] = __builtin_amdgcn_mfma_f32_16x16x32_bf16(pf1, vf1, o[dt], 0, 0, 0);
        }
    }

    {
        float i0 = 1.f / __shfl(lsum, quad * 4 + 0, 64);
        float i1 = 1.f / __shfl(lsum, quad * 4 + 1, 64);
        float i2 = 1.f / __shfl(lsum, quad * 4 + 2, 64);
        float i3 = 1.f / __shfl(lsum, quad * 4 + 3, 64);
        #pragma unroll
        for (int dt = 0; dt < 4; ++dt) {
            size_t col = h * DH + dt * 16 + l16;
            size_t r0  = ((size_t)b * LL + base + quad * 4) * D_MODEL + col;
            out[r0]               = f2bf(o[dt][0] * i0);
            out[r0 + D_MODEL]     = f2bf(o[dt][1] * i1);
            out[r0 + 2 * D_MODEL] = f2bf(o[dt][2] * i2);
            out[r0 + 3 * D_MODEL] = f2bf(o[dt][3] * i3);
        }
    }
}

// ---------------------------------------------------------------------------
extern "C" void kernel_launch(void* const* d_in, const int* in_sizes, int n_in,
                              void* d_out, int out_size, void* d_ws, size_t ws_size,
                              hipStream_t stream)
{
    const float* x    = (const float*)d_in[0];
    // d_in[1] = mask (int32) — causal, handled analytically
    const float* Wqkv = (const float*)d_in[2];
    const float* bqkv = (const float*)d_in[3];
    const float* Wo   = (const float*)d_in[4];
    const float* bo   = (const float*)d_in[5];
    const float* W1   = (const float*)d_in[6];
    const float* b1   = (const float*)d_in[7];
    const float* W2   = (const float*)d_in[8];
    const float* b2   = (const float*)d_in[9];
    const float* ln1a = (const float*)d_in[10];
    const float* ln1b = (const float*)d_in[11];
    const float* ln2a = (const float*)d_in[12];
    const float* ln2b = (const float*)d_in[13];

    char* ws = (char*)d_ws;
    const size_t HSZ = (size_t)BB * NH * LL * DH;      // 4,194,304 elems
    u16*   Qp    = (u16*)ws;
    u16*   Kp    = Qp + HSZ;
    u16*   Vp    = Kp + HSZ;                               // Vt[bh][d][l]
    u16*   attn  = Vp + HSZ;
    u16*   hbuf  = (u16*)ws;                               // alias (QKV/attn dead)
    u16*   xb    = (u16*)(ws + 33554432);                  // bf16 x, 8 MB
    u16*   x1    = (u16*)(ws + 50331648);                  // bf16, 8 MB
    u16*   Wqkvt = (u16*)(ws + 58720256);                  // 3072x1024 bf16
    u16*   Wot   = (u16*)(ws + 65011712);                  // 1024x1024 bf16
    u16*   W1t   = (u16*)(ws + 67108864);                  // 4096x1024 bf16
    u16*   W2t   = (u16*)(ws + 75497472);                  // 1024x4096 bf16
    u16*   Pbuf  = (u16*)(ws + 83886080);                  // up to 4x 4096x1024 bf16

    dim3 blk(256);

    // 0) prep: x->bf16 + Wqkv transpose (only what QKV GEMM needs)
    prep_kernel<<<dim3(2816), blk, 0, stream>>>(x, xb, Wqkv, Wqkvt);

    // 1) qkv = x @ Wqkv + bqkv -> scatter Q(*0.125*log2e), K, Vt (bf16)
    gemm_bt_kernel<0,0,0,1><<<dim3(24, 32), blk, 0, stream>>>(
        xb, Wqkvt, bqkv, nullptr, Qp, Kp, Vp, MROWS, 3 * D_MODEL, D_MODEL);
    // 2) attention -> attn bf16; folds Wo/W1/W2 transposes into idle slots
    attn_kernel<<<dim3(3328), blk, 0, stream>>>(
        Qp, Kp, Vp, attn, Wo, Wot, W1, W1t, W2, W2t);
    // 3) Wo partials (split-K=2)
    gemm_bt_kernel<3,0,0,2><<<dim3(8, 64), blk, 0, stream>>>(
        attn, Wot, bo, nullptr, Pbuf, nullptr, nullptr, MROWS, D_MODEL, D_MODEL);
    // 4) x1 = LN1(sum(P) + bo + x)  (fused reduce+LN, bf16 out)
    lnfuse_kernel<2,1,0><<<dim3(MROWS), blk, 0, stream>>>(
        Pbuf, bo, x, ln1a, ln1b, x1);
    // 5) h = relu(x1 @ W1 + b1)  (bf16 out) — 3-buffer counted pipeline
    gemm256_kernel<2,1><<<dim3(16, 16), dim3(512), 0, stream>>>(
        x1, W1t, b1, hbuf, MROWS, D_FFN, D_MODEL);
    // 6) W2 partials (split-K=4) — 3-buffer counted pipeline
    gemm256_kernel<3,4><<<dim3(4, 64), dim3(512), 0, stream>>>(
        hbuf, W2t, nullptr, Pbuf, MROWS, D_MODEL, D_FFN);
    // 7) out = LN2(sum(P) + b2 + x1)  (fused reduce+LN, fp32 out)
    lnfuse_kernel<4,0,1><<<dim3(MROWS), blk, 0, stream>>>(
        Pbuf, b2, x1, ln2a, ln2b, d_out);
}

// Round 16
// 304.417 us; speedup vs baseline: 1.0617x; 1.0530x over previous
//
#include <hip/hip_runtime.h>

#define D_MODEL 1024
#define D_FFN   4096
#define NH      16
#define DH      64
#define BB      2
#define LL      2048
#define MROWS   (BB * LL)   // 4096

typedef unsigned short u16;
typedef unsigned int   u32;
typedef short bf16x8 __attribute__((ext_vector_type(8)));
typedef float f32x4  __attribute__((ext_vector_type(4)));

__device__ __forceinline__ float bf2f(u16 u) {
    union { u32 i; float f; } v;
    v.i = ((u32)u) << 16;
    return v.f;
}
__device__ __forceinline__ u16 f2bf(float f) {
    union { float f; u32 i; } v;
    v.f = f;
    u32 x = v.i;
    x += 0x7fffu + ((x >> 16) & 1u);   // round to nearest even
    return (u16)(x >> 16);
}
// pack high-16s of two floats (truncating bf16): {lo=a, hi=b}
__device__ __forceinline__ u32 pack_bf_trunc(float a, float b) {
    return __builtin_amdgcn_perm(__float_as_uint(b), __float_as_uint(a),
                                 0x07060302u);
}

// async global->LDS, 16B per lane; ldsptr must be wave-uniform (HW adds lane*16)
typedef const __attribute__((address_space(1))) u32 gu32;
typedef __attribute__((address_space(3))) u32 lu32;
__device__ __forceinline__ void gload_lds16(const void* g, void* l) {
    __builtin_amdgcn_global_load_lds((gu32*)g, (lu32*)l, 16, 0, 0);
}

// ---------------------------------------------------------------------------
// 64x64 fp32->bf16 transpose tile helper (LDS tile passed in)
// ---------------------------------------------------------------------------
__device__ __forceinline__ void wt_tile(
    const float* __restrict__ W, u16* __restrict__ Wt,
    int K, int N, int t, int tid, float* tile /* 64*65 floats */)
{
    const int ntiles = N >> 6;
    const int n0 = (t % ntiles) * 64;
    const int k0 = (t / ntiles) * 64;

    int kr = tid >> 4;             // 0..15
    int nc = (tid & 15) * 4;       // 0..60
    #pragma unroll
    for (int p = 0; p < 4; ++p) {
        float4 v = *(const float4*)&W[(size_t)(k0 + kr + p * 16) * N + n0 + nc];
        tile[(kr + p * 16) * 65 + nc + 0] = v.x;
        tile[(kr + p * 16) * 65 + nc + 1] = v.y;
        tile[(kr + p * 16) * 65 + nc + 2] = v.z;
        tile[(kr + p * 16) * 65 + nc + 3] = v.w;
    }
    __syncthreads();

    int nr = tid >> 2;             // 0..63
    int kc = (tid & 3) * 16;       // 0..48
    u16 o[16];
    #pragma unroll
    for (int j = 0; j < 16; ++j) o[j] = f2bf(tile[(kc + j) * 65 + nr]);
    u16* dst = &Wt[(size_t)(n0 + nr) * K + k0 + kc];
    *(uint4*)dst       = *(const uint4*)&o[0];
    *(uint4*)(dst + 8) = *(const uint4*)&o[8];
}

// ---------------------------------------------------------------------------
// Prep: blocks [0,2048) convert x fp32->bf16; [2048,2816) transpose Wqkv.
// ---------------------------------------------------------------------------
__global__ __launch_bounds__(256) void prep_kernel(
    const float* __restrict__ x,    u16* __restrict__ xb,
    const float* __restrict__ Wqkv, u16* __restrict__ Wqkvt)
{
    __shared__ float tile[64 * 65];
    const int tid = threadIdx.x;
    const int bi  = blockIdx.x;

    if (bi < 2048) {   // x convert
        int i = bi * 2048 + tid * 8;
        float4 a = *(const float4*)(x + i);
        float4 b = *(const float4*)(x + i + 4);
        u16 o[8] = {f2bf(a.x), f2bf(a.y), f2bf(a.z), f2bf(a.w),
                    f2bf(b.x), f2bf(b.y), f2bf(b.z), f2bf(b.w)};
        *(uint4*)(xb + i) = *(const uint4*)o;
        return;
    }
    wt_tile(Wqkv, Wqkvt, 1024, 3072, bi - 2048, tid, tile);
}

// ---------------------------------------------------------------------------
// MFMA bf16 GEMM, m97-style, XCD remap, optional split-K. R13: steps 5/6
// reverted to this kernel — three gemm256 schedule variants (1-phase counted,
// 4-phase drain0, 3-buf 2-deep counted) all measured neutral-to-worse at
// K=1024 / 1-2 blocks/CU; this 128^2 4-blocks/CU structure is measured best.
// EPI 0: scatter Q(x0.125*log2e)/K bf16; V cols take transposed epilogue.
// EPI 2: ReLU bf16. EPI 3: bf16 partial (no bias) -> out0v[s*M*N + ...].
// ---------------------------------------------------------------------------
template <int EPI, int RF32, int OF32, int KS>
__global__ __launch_bounds__(256, 4) void gemm_bt_kernel(
    const u16* __restrict__ A, const u16* __restrict__ Bt,
    const float* __restrict__ bias, const void* __restrict__ resv,
    void* __restrict__ out0v, u16* __restrict__ out1, u16* __restrict__ out2,
    int M, int N, int K)
{
    __shared__ u16 smem[16384];    // 32 KB: sA|sB staging; V-transpose tile
    u16* sA = smem;                // 128*64
    u16* sB = smem + 8192;         // 128*64

    const int tid  = threadIdx.x;
    const int lane = tid & 63;
    const int wave = tid >> 6;
    const int wm   = (wave & 1) * 64;
    const int wn   = (wave >> 1) * 64;
    const int quad = lane >> 4;
    const int l16  = lane & 15;

    // XCD-locality remap (requires gridDim.x % 2 == 0, gridDim.y % 4 == 0)
    const int nb  = gridDim.x;
    const int mb  = gridDim.y;
    const int f   = blockIdx.y * nb + blockIdx.x;   // dispatch-linear id
    const int xcd = f & 7;
    const int idx = f >> 3;
    const int rn  = nb >> 1;                        // region width  (tiles)
    const int rm  = mb >> 2;                        // region height (tiles)
    const int n0  = ((xcd & 1) * rn + (idx % rn)) * 128;
    const int ym  = (xcd >> 1) * rm + (idx / rn);   // 0..mb-1

    int s, m0;
    if (KS > 1) {
        const int mt = mb / KS;
        s  = ym / mt;
        m0 = (ym % mt) * 128;
    } else {
        s  = 0;
        m0 = ym * 128;
    }
    const int Kseg = K / KS;
    const int kbeg = s * Kseg;

    f32x4 acc[4][4];
    #pragma unroll
    for (int i = 0; i < 4; ++i)
        #pragma unroll
        for (int j = 0; j < 4; ++j)
            acc[i][j] = (f32x4){0.f, 0.f, 0.f, 0.f};

    const u16* Ablk = A  + (size_t)m0 * K;
    const u16* Bblk = Bt + (size_t)n0 * K;

    for (int k0 = kbeg; k0 < kbeg + Kseg; k0 += 64) {
        #pragma unroll
        for (int i = 0; i < 4; ++i) {
            int chunk = (i * 4 + wave) * 64 + lane;        // 0..1023
            int r = chunk >> 3;                            // row 0..127
            int c = (chunk & 7) ^ (r & 7);                 // swizzled k-chunk
            size_t goff = (size_t)r * K + k0 + c * 8;
            gload_lds16(Ablk + goff, &sA[(i * 4 + wave) * 512]);
            gload_lds16(Bblk + goff, &sB[(i * 4 + wave) * 512]);
        }
        __syncthreads();

        #pragma unroll
        for (int ks = 0; ks < 2; ++ks) {
            bf16x8 af[4], bfr[4];
            #pragma unroll
            for (int i = 0; i < 4; ++i) {
                int R = wm + i * 16 + l16;
                int slot = R * 8 + ((ks * 4 + quad) ^ (R & 7));
                af[i] = *(const bf16x8*)&sA[slot * 8];
            }
            #pragma unroll
            for (int j = 0; j < 4; ++j) {
                int R = wn + j * 16 + l16;
                int slot = R * 8 + ((ks * 4 + quad) ^ (R & 7));
                bfr[j] = *(const bf16x8*)&sB[slot * 8];
            }
            #pragma unroll
            for (int i = 0; i < 4; ++i)
                #pragma unroll
                for (int j = 0; j < 4; ++j)
                    acc[i][j] = __builtin_amdgcn_mfma_f32_16x16x32_bf16(
                        af[i], bfr[j], acc[i][j], 0, 0, 0);
        }
        __syncthreads();
    }

    // --- V-transpose epilogue (EPI 0, V columns): write Vt[bh][d][l] ---
    if (EPI == 0 && n0 >= 2 * D_MODEL) {
        u16* tile = smem;                       // 128x128 u16 = 32 KB
        #pragma unroll
        for (int i = 0; i < 4; ++i) {
            int rl = wm + i * 16 + quad * 4;    // local row (l) base
            #pragma unroll
            for (int j = 0; j < 4; ++j) {
                int cl = wn + j * 16 + l16;     // local col (d)
                float bv = bias[n0 + cl];
                int sx = 8 * (cl & 15);         // XOR swizzle (8-aligned)
                #pragma unroll
                for (int r = 0; r < 4; ++r)
                    tile[cl * 128 + ((rl + r) ^ sx)] = f2bf(acc[i][j][r] + bv);
            }
        }
        __syncthreads();
        int cl  = tid >> 1;                     // local col 0..127
        int rb  = (tid & 1) * 64;               // row half
        int col = n0 + cl;
        int h   = (col >> 6) & 15;
        int d   = col & 63;
        int b   = m0 >> 11;
        int l0  = (m0 & 2047) + rb;
        int sx  = 8 * (cl & 15);
        u16* dst = out2 + ((size_t)(b * NH + h) * DH + d) * LL + l0;
        #pragma unroll
        for (int u = 0; u < 8; ++u) {
            uint4 q = *(const uint4*)&tile[cl * 128 + ((rb + 8 * u) ^ sx)];
            *(uint4*)(dst + 8 * u) = q;
        }
        return;
    }

    #pragma unroll
    for (int i = 0; i < 4; ++i) {
        int rowb = m0 + wm + i * 16 + quad * 4;
        #pragma unroll
        for (int j = 0; j < 4; ++j) {
            int col = n0 + wn + j * 16 + l16;
            float bv = (EPI == 3) ? 0.f : bias[col];
            #pragma unroll
            for (int r = 0; r < 4; ++r) {
                int rr = rowb + r;
                float v = acc[i][j][r] + bv;
                if (EPI == 0) {
                    int h     = (col >> 6) & 15;
                    int d     = col & 63;
                    int b     = rr >> 11;
                    int l     = rr & 2047;
                    size_t idx2 = ((size_t)(b * NH + h) * LL + l) * DH + d;
                    u16* o0 = (u16*)out0v;
                    // Q pre-scaled by 0.125 * log2(e) so attention can use
                    // exp2 directly (softmax is scale-consistent).
                    if (col < D_MODEL)  o0[idx2]   = f2bf(v * 0.18033688f);
                    else                out1[idx2] = f2bf(v);
                } else if (EPI == 3) {
                    ((u16*)out0v)[((size_t)s * M + rr) * N + col] = f2bf(v);
                } else {
                    size_t idx2 = (size_t)rr * N + col;
                    if (EPI == 1) {
                        v += RF32 ? ((const float*)resv)[idx2]
                                  : bf2f(((const u16*)resv)[idx2]);
                    } else {  // EPI == 2: ReLU
                        v = v > 0.f ? v : 0.f;
                    }
                    if (OF32) ((float*)out0v)[idx2] = v;
                    else      ((u16*)out0v)[idx2]   = f2bf(v);
                }
            }
        }
    }
}

// ---------------------------------------------------------------------------
// Fused split-K reduce + LayerNorm. One block per row.
// ---------------------------------------------------------------------------
template <int KS, int RF32, int OF32>
__global__ __launch_bounds__(256) void lnfuse_kernel(
    const u16* __restrict__ P, const float* __restrict__ bias,
    const void* __restrict__ resv,
    const float* __restrict__ ga, const float* __restrict__ gb,
    void* __restrict__ outv)
{
    __shared__ float red[8];
    const int tid  = threadIdx.x;
    const int lane = tid & 63;
    const int wave = tid >> 6;
    const size_t row = blockIdx.x;
    const size_t SL  = (size_t)MROWS * D_MODEL;
    const int c = tid * 4;

    float v0, v1, v2, v3;
    {
        float4 bv = *(const float4*)(bias + c);
        v0 = bv.x; v1 = bv.y; v2 = bv.z; v3 = bv.w;
    }
    #pragma unroll
    for (int s = 0; s < KS; ++s) {
        uint2 p = *(const uint2*)(P + s * SL + row * D_MODEL + c);
        v0 += bf2f((u16)p.x); v1 += bf2f((u16)(p.x >> 16));
        v2 += bf2f((u16)p.y); v3 += bf2f((u16)(p.y >> 16));
    }
    if (RF32) {
        float4 r = *(const float4*)((const float*)resv + row * D_MODEL + c);
        v0 += r.x; v1 += r.y; v2 += r.z; v3 += r.w;
    } else {
        uint2 r = *(const uint2*)((const u16*)resv + row * D_MODEL + c);
        v0 += bf2f((u16)r.x); v1 += bf2f((u16)(r.x >> 16));
        v2 += bf2f((u16)r.y); v3 += bf2f((u16)(r.y >> 16));
    }

    float s_ = v0 + v1 + v2 + v3;
    #pragma unroll
    for (int o = 32; o > 0; o >>= 1) s_ += __shfl_xor(s_, o, 64);
    if (lane == 0) red[wave] = s_;
    __syncthreads();
    float mean = (red[0] + red[1] + red[2] + red[3]) * (1.f / 1024.f);

    float d0 = v0 - mean, d1 = v1 - mean, d2 = v2 - mean, d3 = v3 - mean;
    float q = d0 * d0 + d1 * d1 + d2 * d2 + d3 * d3;
    #pragma unroll
    for (int o = 32; o > 0; o >>= 1) q += __shfl_xor(q, o, 64);
    if (lane == 0) red[4 + wave] = q;
    __syncthreads();
    float var = (red[4] + red[5] + red[6] + red[7]) * (1.f / 1023.f);
    float inv = 1.f / (sqrtf(var) + 1e-6f);

    float y0 = d0 * inv * ga[c + 0] + gb[c + 0];
    float y1 = d1 * inv * ga[c + 1] + gb[c + 1];
    float y2 = d2 * inv * ga[c + 2] + gb[c + 2];
    float y3 = d3 * inv * ga[c + 3] + gb[c + 3];
    if (OF32) {
        float4 y = {y0, y1, y2, y3};
        *(float4*)((float*)outv + row * D_MODEL + c) = y;
    } else {
        ushort4 y = {f2bf(y0), f2bf(y1), f2bf(y2), f2bf(y3)};
        *(ushort4*)((u16*)outv + row * D_MODEL + c) = y;
    }
}

// ---------------------------------------------------------------------------
// MFMA flash attention (causal) + FOLDED WEIGHT TRANSPOSES.
// 1024 independent single-q-tile blocks, XCD remap, balanced qt map
// (per-CU iteration sum == 66 for every CU). V arrives transposed
// (Vt[bh][d][l]); staging = 2 uint4 loads + 2 swizzled ds_write_b128.
// R13: s_setprio(1) wrapped around the QK^T and PV MFMA clusters (T5).
// Mechanism: 4-5 independent blocks/CU at different phases; boosting the
// MFMA-entering wave's priority lets it pre-empt other blocks' exp2/staging
// VALU streams (m191: +4-7% on attn; null only for lockstep waves, m190).
// blocks [0,1024): attention; [1024,3328): Wo/W1/W2 64x64 transpose tiles.
// Softmax uses exp2 (Q pre-scaled by 0.125*log2e at QKV epilogue).
// ---------------------------------------------------------------------------
__global__ __launch_bounds__(256) void attn_kernel(
    const u16* __restrict__ Q, const u16* __restrict__ K,
    const u16* __restrict__ V, u16* __restrict__ out,
    const float* __restrict__ Wo, u16* __restrict__ Wot,
    const float* __restrict__ W1, u16* __restrict__ W1t,
    const float* __restrict__ W2, u16* __restrict__ W2t)
{
    __shared__ u16 smem[13824];   // 27648 B: ks|vs|ps for attn, tile for wt
    u16* ks = smem;                       // 64*72
    u16* vs = smem + 4608;                // 64*72
    u16* ps = smem + 9216;                // 4 waves * 16*72

    const int tid  = threadIdx.x;
    const int bi   = blockIdx.x;

    if (bi >= 1024) {   // ---- weight transpose blocks ----
        float* tile = (float*)smem;       // 64*65 floats = 16640 B
        int t = bi - 1024;
        if (t < 256)       wt_tile(Wo, Wot, 1024, 1024, t,        tid, tile);
        else if (t < 1280) wt_tile(W1, W1t, 1024, 4096, t - 256,  tid, tile);
        else               wt_tile(W2, W2t, 4096, 1024, t - 1280, tid, tile);
        return;
    }

    const int lane = tid & 63;
    const int wave = tid >> 6;
    const int l16  = lane & 15;
    const int quad = lane >> 4;

    // 8 XCDs x (4 heads x 32 q-tiles); balanced qt map (see header).
    const int xcd = bi & 7;
    const int idx = bi >> 3;            // 0..127
    const int bh  = xcd * 4 + (idx & 3);
    const int j   = idx >> 2;           // 0..31
    const int qt  = (j < 16) ? (31 - j) : (j - 16);
    const int b   = bh >> 4, h = bh & 15;
    const size_t head_off = (size_t)bh * LL * DH;

    const u16* Qh = Q + head_off;
    const u16* Kh = K + head_off;
    const u16* Vh = V + head_off;       // Vt layout: [d][l]

    const int base = qt * 64 + wave * 16;
    const int qg   = base + l16;

    const bf16x8 qf0 = *(const bf16x8*)&Qh[(size_t)qg * DH + quad * 8];
    const bf16x8 qf1 = *(const bf16x8*)&Qh[(size_t)qg * DH + 32 + quad * 8];

    float lsum = 0.f;
    f32x4 o[4];
    #pragma unroll
    for (int t = 0; t < 4; ++t) o[t] = (f32x4){0.f, 0.f, 0.f, 0.f};

    u16* psw = ps + wave * 1152;         // 16*72 per wave

    const int key = tid >> 2;            // 0..63 (K: key row; V: d row)
    const int kd0 = (tid & 3) * 16;      // 0,16,32,48 (K: d seg; V: key seg)

    // V swizzle constants (loop-invariant): vs32[d*36 + (kp ^ C)], C=4*((d>>3)&7)
    const int vC    = 4 * ((key >> 3) & 7);
    const int vbase = (kd0 >> 1) ^ (vC & 24);   // kp0 = kd0/2, 8-aligned run
    const int vofA  = vbase + (vC & 4);
    const int vofB  = vbase + ((vC & 4) ^ 4);
    u32* vs32 = (u32*)vs;

    uint4 kr0, kr1, vr0, vr1;
    {
        const u16* ksrc = Kh + (size_t)key * DH + kd0;
        kr0 = *(const uint4*)ksrc;
        kr1 = *(const uint4*)(ksrc + 8);
        const u16* vsrc = Vh + (size_t)key * LL + kd0;
        vr0 = *(const uint4*)vsrc;
        vr1 = *(const uint4*)(vsrc + 8);
    }

    for (int c = 0; c <= qt; ++c) {
        __syncthreads();
        *(uint4*)&ks[key * 72 + kd0]     = kr0;
        *(uint4*)&ks[key * 72 + kd0 + 8] = kr1;
        *(uint4*)&vs32[key * 36 + vofA]  = vr0;
        *(uint4*)&vs32[key * 36 + vofB]  = vr1;
        __syncthreads();
        if (c < qt) {
            const u16* ksrc = Kh + (size_t)((c + 1) * 64 + key) * DH + kd0;
            kr0 = *(const uint4*)ksrc;
            kr1 = *(const uint4*)(ksrc + 8);
            const u16* vsrc = Vh + (size_t)key * LL + (c + 1) * 64 + kd0;
            vr0 = *(const uint4*)vsrc;
            vr1 = *(const uint4*)(vsrc + 8);
        }

        f32x4 st[4];
        __builtin_amdgcn_s_setprio(1);
        #pragma unroll
        for (int t = 0; t < 4; ++t) {
            bf16x8 k0 = *(const bf16x8*)&ks[(t * 16 + l16) * 72 + quad * 8];
            bf16x8 k1 = *(const bf16x8*)&ks[(t * 16 + l16) * 72 + 32 + quad * 8];
            f32x4 s = (f32x4){0.f, 0.f, 0.f, 0.f};
            s = __builtin_amdgcn_mfma_f32_16x16x32_bf16(k0, qf0, s, 0, 0, 0);
            s = __builtin_amdgcn_mfma_f32_16x16x32_bf16(k1, qf1, s, 0, 0, 0);
            st[t] = s;
        }
        __builtin_amdgcn_s_setprio(0);

        if (c == qt) {
            #pragma unroll
            for (int t = 0; t < 4; ++t)
                #pragma unroll
                for (int r = 0; r < 4; ++r)
                    if (c * 64 + t * 16 + quad * 4 + r > qg) st[t][r] = -INFINITY;
        }

        {
            float psum = 0.f;
            #pragma unroll
            for (int t = 0; t < 4; ++t) {
                float p0 = exp2f(st[t][0]), p1 = exp2f(st[t][1]);
                float p2 = exp2f(st[t][2]), p3 = exp2f(st[t][3]);
                psum += (p0 + p1) + (p2 + p3);
                uint2 w = {pack_bf_trunc(p0, p1), pack_bf_trunc(p2, p3)};
                *(uint2*)&psw[l16 * 72 + t * 16 + quad * 4] = w;
            }
            psum += __shfl_xor(psum, 16, 64);
            psum += __shfl_xor(psum, 32, 64);
            lsum += psum;
        }

        bf16x8 pf0 = *(const bf16x8*)&psw[l16 * 72 + quad * 8];
        bf16x8 pf1 = *(const bf16x8*)&psw[l16 * 72 + 32 + quad * 8];

        __builtin_amdgcn_s_setprio(1);
        #pragma unroll
        for (int dt = 0; dt < 4; ++dt) {
            int d  = dt * 16 + l16;
            int sw = 4 * ((d >> 3) & 7);
            bf16x8 vf0 = *(const bf16x8*)&vs[d * 72 + 2 * ((quad * 4) ^ sw)];
            bf16x8 vf1 = *(const bf16x8*)&vs[d * 72 + 2 * ((16 + quad * 4) ^ sw)];
            o[dt] = __builtin_amdgcn_mfma_f32_16x16x32_bf16(pf0, vf0, o[dt], 0, 0, 0);
            o[dt] = __builtin_amdgcn_mfma_f32_16x16x32_bf16(pf1, vf1, o[dt], 0, 0, 0);
        }
        __builtin_amdgcn_s_setprio(0);
    }

    {
        float i0 = 1.f / __shfl(lsum, quad * 4 + 0, 64);
        float i1 = 1.f / __shfl(lsum, quad * 4 + 1, 64);
        float i2 = 1.f / __shfl(lsum, quad * 4 + 2, 64);
        float i3 = 1.f / __shfl(lsum, quad * 4 + 3, 64);
        #pragma unroll
        for (int dt = 0; dt < 4; ++dt) {
            size_t col = h * DH + dt * 16 + l16;
            size_t r0  = ((size_t)b * LL + base + quad * 4) * D_MODEL + col;
            out[r0]               = f2bf(o[dt][0] * i0);
            out[r0 + D_MODEL]     = f2bf(o[dt][1] * i1);
            out[r0 + 2 * D_MODEL] = f2bf(o[dt][2] * i2);
            out[r0 + 3 * D_MODEL] = f2bf(o[dt][3] * i3);
        }
    }
}

// ---------------------------------------------------------------------------
extern "C" void kernel_launch(void* const* d_in, const int* in_sizes, int n_in,
                              void* d_out, int out_size, void* d_ws, size_t ws_size,
                              hipStream_t stream)
{
    const float* x    = (const float*)d_in[0];
    // d_in[1] = mask (int32) — causal, handled analytically
    const float* Wqkv = (const float*)d_in[2];
    const float* bqkv = (const float*)d_in[3];
    const float* Wo   = (const float*)d_in[4];
    const float* bo   = (const float*)d_in[5];
    const float* W1   = (const float*)d_in[6];
    const float* b1   = (const float*)d_in[7];
    const float* W2   = (const float*)d_in[8];
    const float* b2   = (const float*)d_in[9];
    const float* ln1a = (const float*)d_in[10];
    const float* ln1b = (const float*)d_in[11];
    const float* ln2a = (const float*)d_in[12];
    const float* ln2b = (const float*)d_in[13];

    char* ws = (char*)d_ws;
    const size_t HSZ = (size_t)BB * NH * LL * DH;      // 4,194,304 elems
    u16*   Qp    = (u16*)ws;
    u16*   Kp    = Qp + HSZ;
    u16*   Vp    = Kp + HSZ;                               // Vt[bh][d][l]
    u16*   attn  = Vp + HSZ;
    u16*   hbuf  = (u16*)ws;                               // alias (QKV/attn dead)
    u16*   xb    = (u16*)(ws + 33554432);                  // bf16 x, 8 MB
    u16*   x1    = (u16*)(ws + 50331648);                  // bf16, 8 MB
    u16*   Wqkvt = (u16*)(ws + 58720256);                  // 3072x1024 bf16
    u16*   Wot   = (u16*)(ws + 65011712);                  // 1024x1024 bf16
    u16*   W1t   = (u16*)(ws + 67108864);                  // 4096x1024 bf16
    u16*   W2t   = (u16*)(ws + 75497472);                  // 1024x4096 bf16
    u16*   Pbuf  = (u16*)(ws + 83886080);                  // up to 4x 4096x1024 bf16

    dim3 blk(256);

    // 0) prep: x->bf16 + Wqkv transpose (only what QKV GEMM needs)
    prep_kernel<<<dim3(2816), blk, 0, stream>>>(x, xb, Wqkv, Wqkvt);

    // 1) qkv = x @ Wqkv + bqkv -> scatter Q(*0.125*log2e), K, Vt (bf16)
    gemm_bt_kernel<0,0,0,1><<<dim3(24, 32), blk, 0, stream>>>(
        xb, Wqkvt, bqkv, nullptr, Qp, Kp, Vp, MROWS, 3 * D_MODEL, D_MODEL);
    // 2) attention -> attn bf16; folds Wo/W1/W2 transposes into idle slots
    attn_kernel<<<dim3(3328), blk, 0, stream>>>(
        Qp, Kp, Vp, attn, Wo, Wot, W1, W1t, W2, W2t);
    // 3) Wo partials (split-K=2)
    gemm_bt_kernel<3,0,0,2><<<dim3(8, 64), blk, 0, stream>>>(
        attn, Wot, bo, nullptr, Pbuf, nullptr, nullptr, MROWS, D_MODEL, D_MODEL);
    // 4) x1 = LN1(sum(P) + bo + x)  (fused reduce+LN, bf16 out)
    lnfuse_kernel<2,1,0><<<dim3(MROWS), blk, 0, stream>>>(
        Pbuf, bo, x, ln1a, ln1b, x1);
    // 5) h = relu(x1 @ W1 + b1)  (bf16 out)
    gemm_bt_kernel<2,0,0,1><<<dim3(32, 32), blk, 0, stream>>>(
        x1, W1t, b1, nullptr, hbuf, nullptr, nullptr, MROWS, D_FFN, D_MODEL);
    // 6) W2 partials (split-K=4)
    gemm_bt_kernel<3,0,0,4><<<dim3(8, 128), blk, 0, stream>>>(
        hbuf, W2t, b2, nullptr, Pbuf, nullptr, nullptr, MROWS, D_MODEL, D_FFN);
    // 7) out = LN2(sum(P) + b2 + x1)  (fused reduce+LN, fp32 out)
    lnfuse_kernel<4,0,1><<<dim3(MROWS), blk, 0, stream>>>(
        Pbuf, b2, x1, ln2a, ln2b, d_out);
}